// Round 16
// baseline (376.906 us; speedup 1.0000x reference)
//
#include <hip/hip_runtime.h>

#define TOKS 100352   // BT*L = 32*3136
#define LDIM 3136     // H*W
#define SCALE_F 0.17677669529663687f  // 32^-0.5

typedef unsigned short u16;
typedef u16   u16x8 __attribute__((ext_vector_type(8)));
typedef short s16x8 __attribute__((ext_vector_type(8)));
typedef float f32x8 __attribute__((ext_vector_type(8)));
typedef float f32x4 __attribute__((ext_vector_type(4)));

__device__ __forceinline__ float bf2f(u16 u){ return __uint_as_float(((unsigned)u)<<16); }
__device__ __forceinline__ u16 f2bf(float f){
  unsigned u = __float_as_uint(f);
  return (u16)((u + 0x7FFFu + ((u>>16)&1u)) >> 16);   // RNE
}
// packed bf16 convert: lo=cvt(a), hi=cvt(b)  (RNE) — single VALU instr
__device__ __forceinline__ unsigned cvtpk(float a, float b){
  unsigned r;
  asm("v_cvt_pk_bf16_f32 %0, %1, %2" : "=v"(r) : "v"(a), "v"(b));
  return r;
}
__device__ __forceinline__ f32x8 ldbf8(const u16* p){
  u16x8 u = *(const u16x8*)p;
  f32x8 f;
  #pragma unroll
  for (int j=0;j<8;j++) f[j] = bf2f(u[j]);
  return f;
}
__device__ __forceinline__ u16x8 pack8(f32x8 v){
  u16x8 r;
  #pragma unroll
  for (int j=0;j<8;j++) r[j] = f2bf(v[j]);
  return r;
}
__device__ __forceinline__ float sum8(f32x8 a){
  return ((a[0]+a[1])+(a[2]+a[3]))+((a[4]+a[5])+(a[6]+a[7]));
}
// sigmoid-form gelu: x*sigmoid(1.702x). |err| <~0.005 for |x|<1 (our pre-act range)
__device__ __forceinline__ float gelu_f(float x){
  return x / (1.0f + __expf(-1.702f*x));
}

// ---- async global->LDS, 16B per lane; LDS dest = wave-uniform base + lane*16 ----
__device__ __forceinline__ void gl16(const u16* g, u16* l){
  __builtin_amdgcn_global_load_lds(
      (const __attribute__((address_space(1))) unsigned*)(const void*)g,
      (__attribute__((address_space(3))) unsigned*)(void*)l, 16, 0, 0);
}
// stage ROWS x 128 bf16 tile into XOR-swizzled LDS (slot = kb ^ (r&7)) via
// pre-swizzled per-lane SOURCE (rule: linear dest + inverse-swz source + swz read).
template<int ITERS>
__device__ __forceinline__ void stage_tileN(const u16* __restrict__ src, size_t rowstart,
    int KTOT, int koff, u16* lds, int wv, int lane){
  const int rr = wv*4 + (lane>>4);
  const int sl = lane&15;
  const int kb = sl ^ (rr&7);
  const u16* g0 = src + (rowstart + rr)*(size_t)KTOT + koff + kb*8;
  u16* l0 = lds + wv*4*128;
  #pragma unroll
  for (int it=0; it<ITERS; it++)
    gl16(g0 + (size_t)it*16*KTOT, l0 + it*16*128);
}
__device__ __forceinline__ void stage_tile(const u16* __restrict__ src, size_t rowstart,
    int KTOT, int koff, u16* lds, int wv, int lane){
  stage_tileN<8>(src, rowstart, KTOT, koff, lds, wv, lane);
}

// ---------------- weight prep: f32 (K,N) -> bf16 transposed (N,K) ----------------
struct WSrc { const float* p[10]; };
__global__ __launch_bounds__(256) void prep_w(WSrc s, u16* __restrict__ dst){
  const int Ks[10]={128,128,128,512,128,32,128,32,128,32};
  const int Ns[10]={384,128,512,128,32,128,32,128,32,128};
  const int off[11]={0,49152,65536,131072,196608,200704,204800,208896,212992,217088,221184};
  int idx = blockIdx.x*256+threadIdx.x;
  int m=0;
  #pragma unroll
  for (int i=0;i<10;i++) if (idx>=off[i+1]) m=i+1;
  int e = idx-off[m];
  int K=Ks[m], Nn=Ns[m];
  int n=e/K, k=e-n*K;
  dst[idx] = f2bf(s.p[m][k*Nn+n]);
}

// ---------------- LayerNorm: one wave per token (C=128), bf16 out ----------------
__global__ __launch_bounds__(256) void ln_kernel(const float* __restrict__ x,
    const float* __restrict__ g, const float* __restrict__ bta, u16* __restrict__ out)
{
  int tok  = (int)((blockIdx.x*256u + threadIdx.x) >> 6);
  int lane = threadIdx.x & 63;
  const float* xr = x + (size_t)tok*128;
  float v0 = xr[lane], v1 = xr[lane+64];
  float s = v0+v1;
  #pragma unroll
  for (int o=32;o;o>>=1) s += __shfl_xor(s,o);
  float m = s*(1.0f/128.0f);
  float d0=v0-m, d1=v1-m;
  float q = d0*d0+d1*d1;
  #pragma unroll
  for (int o=32;o;o>>=1) q += __shfl_xor(q,o);
  float rs = rsqrtf(q*(1.0f/128.0f)+1e-5f);
  u16* orow = out + (size_t)tok*128;
  orow[lane]    = f2bf(d0*rs*g[lane]   + bta[lane]);
  orow[lane+64] = f2bf(d1*rs*g[lane+64]+ bta[lane+64]);
}

// ======== Tiled MFMA GEMM, SWAPPED operands: D[col @ lr*4+r][row @ lc] ========
// EPI: 0 = bf16 bias (direct uint2 stores); 1 = + gelu
template<int KCH, int NTC, int EPI>
__global__ __launch_bounds__(256,2) void gemm_tile(
    const u16* __restrict__ X, const u16* __restrict__ WT,
    const float* __restrict__ bias, void* outp, int N,
    const float* res1, const u16* __restrict__ adab)
{
  constexpr int KTOT = KCH*128;
  __shared__ u16 As[128*128];
  __shared__ u16 Bs[128*128];
  const int tid = threadIdx.x;
  const int wv = tid>>6, lane = tid&63, lr = lane>>4, lc = lane&15;
  const int wr = wv>>1, wc = wv&1;
  const size_t row0 = (size_t)blockIdx.x*128;

  f32x4 acc[4][4];
  #pragma unroll
  for (int mi=0;mi<4;mi++)
    #pragma unroll
    for (int nj=0;nj<4;nj++) acc[mi][nj] = (f32x4){0.f,0.f,0.f,0.f};

  for (int kc=0; kc<KCH; kc++){
    for (int nt=0; nt<NTC; nt++){
      if (kc+nt > 0) __syncthreads();
      if (nt == 0) stage_tile(X, row0, KTOT, kc*128, As, wv, lane);
      stage_tile(WT, (size_t)nt*128, KTOT, kc*128, Bs, wv, lane);
      __syncthreads();
      #pragma unroll
      for (int kt=0; kt<4; kt++){
        s16x8 af[4], bfr[4];
        #pragma unroll
        for (int mi=0;mi<4;mi++){
          int row = wr*64 + mi*16 + lc;
          af[mi] = *(const s16x8*)&As[row*128 + (((kt*4+lr) ^ (lc&7))*8)];
        }
        #pragma unroll
        for (int nj=0;nj<4;nj++){
          int col = wc*64 + nj*16 + lc;
          bfr[nj] = *(const s16x8*)&Bs[col*128 + (((kt*4+lr) ^ (lc&7))*8)];
        }
        #pragma unroll
        for (int mi=0;mi<4;mi++)
          #pragma unroll
          for (int nj=0;nj<4;nj++)
            acc[mi][nj] = __builtin_amdgcn_mfma_f32_16x16x32_bf16(bfr[nj], af[mi], acc[mi][nj], 0,0,0);
      }
      {
        #pragma unroll
        for (int nj=0;nj<4;nj++){
          const int colb = nt*128 + wc*64 + nj*16 + lr*4;
          float4 b4 = *(const float4*)&bias[colb];
          #pragma unroll
          for (int mi=0;mi<4;mi++){
            const size_t row = row0 + wr*64 + mi*16 + lc;
            float v0=acc[mi][nj][0]+b4.x, v1=acc[mi][nj][1]+b4.y,
                  v2=acc[mi][nj][2]+b4.z, v3=acc[mi][nj][3]+b4.w;
            if constexpr (EPI==1){ v0=gelu_f(v0); v1=gelu_f(v1); v2=gelu_f(v2); v3=gelu_f(v3); }
            uint2 pk; pk.x = cvtpk(v0,v1); pk.y = cvtpk(v2,v3);
            *(uint2*)&((u16*)outp)[row*(size_t)N + colb] = pk;
            acc[mi][nj] = (f32x4){0.f,0.f,0.f,0.f};
          }
        }
      }
    }
  }
  (void)res1; (void)adab;
}

// ======== Fused proj + adapter + residual + LayerNorm (row-local) ========
template<int SMODE>
__global__ __launch_bounds__(256,2) void proj_ada_tile(
    const u16* __restrict__ O, const u16* __restrict__ PW, const float* __restrict__ pb,
    const u16* __restrict__ W1T, const float* __restrict__ b1,
    const u16* __restrict__ W2T, const float* __restrict__ b2,
    const float* __restrict__ res1, float* __restrict__ outp,
    const float* __restrict__ gn, const float* __restrict__ gb, u16* __restrict__ xnout)
{
  __shared__ u16 As[128*128];
  __shared__ u16 Bs[128*128];
  __shared__ u16 Hs[4][32][40];
  const int tid = threadIdx.x;
  const int wv = tid>>6, lane = tid&63, lr = lane>>4, lc = lane&15;
  const int wr = wv>>1, wc = wv&1;
  const size_t row0 = (size_t)blockIdx.x*128;
  stage_tile(O, row0, 128, 0, As, wv, lane);
  stage_tile(PW, 0, 128, 0, Bs, wv, lane);
  __syncthreads();
  f32x4 acc[4][4];
  #pragma unroll
  for (int mi=0;mi<4;mi++)
    #pragma unroll
    for (int nj=0;nj<4;nj++) acc[mi][nj] = (f32x4){0.f,0.f,0.f,0.f};
  #pragma unroll
  for (int kt=0; kt<4; kt++){
    s16x8 af[4], bfr[4];
    #pragma unroll
    for (int mi=0;mi<4;mi++)
      af[mi] = *(const s16x8*)&As[(wr*64+mi*16+lc)*128 + (((kt*4+lr) ^ (lc&7))*8)];
    #pragma unroll
    for (int nj=0;nj<4;nj++)
      bfr[nj] = *(const s16x8*)&Bs[(wc*64+nj*16+lc)*128 + (((kt*4+lr) ^ (lc&7))*8)];
    #pragma unroll
    for (int mi=0;mi<4;mi++)
      #pragma unroll
      for (int nj=0;nj<4;nj++)
        acc[mi][nj] = __builtin_amdgcn_mfma_f32_16x16x32_bf16(bfr[nj], af[mi], acc[mi][nj], 0,0,0);
  }
  __syncthreads();
  #pragma unroll
  for (int nj=0;nj<4;nj++){
    const int colb = wc*64 + nj*16 + lr*4;
    float4 b4 = *(const float4*)&pb[colb];
    #pragma unroll
    for (int mi=0;mi<4;mi++){
      const int row = wr*64 + mi*16 + lc;
      uint2 pk;
      pk.x = cvtpk(acc[mi][nj][0]+b4.x, acc[mi][nj][1]+b4.y);
      pk.y = cvtpk(acc[mi][nj][2]+b4.z, acc[mi][nj][3]+b4.w);
      *(uint2*)&As[row*128 + (((colb>>3) ^ (row&7))*8) + (colb&7)] = pk;
    }
  }
  __syncthreads();
  const int rbase = wv*32;
  f32x4 a2[2][2];
  #pragma unroll
  for (int mi=0;mi<2;mi++){ a2[mi][0]=(f32x4){0.f,0.f,0.f,0.f}; a2[mi][1]=(f32x4){0.f,0.f,0.f,0.f}; }
  #pragma unroll
  for (int kt=0; kt<4; kt++){
    s16x8 af0 = *(const s16x8*)&As[(rbase+lc)*128 + (((kt*4+lr) ^ (lc&7))*8)];
    s16x8 af1 = *(const s16x8*)&As[(rbase+16+lc)*128 + (((kt*4+lr) ^ (lc&7))*8)];
    #pragma unroll
    for (int nj=0; nj<2; nj++){
      s16x8 b = *(const s16x8*)&W1T[(size_t)(nj*16+lc)*128 + kt*32 + lr*8];
      a2[0][nj] = __builtin_amdgcn_mfma_f32_16x16x32_bf16(b, af0, a2[0][nj], 0,0,0);
      a2[1][nj] = __builtin_amdgcn_mfma_f32_16x16x32_bf16(b, af1, a2[1][nj], 0,0,0);
    }
  }
  #pragma unroll
  for (int nj=0;nj<2;nj++){
    const int hb = nj*16 + lr*4;
    float4 b4 = *(const float4*)&b1[hb];
    #pragma unroll
    for (int mi=0;mi<2;mi++){
      const int tok = mi*16 + lc;
      uint2 pk;
      pk.x = cvtpk(gelu_f(a2[mi][nj][0]+b4.x), gelu_f(a2[mi][nj][1]+b4.y));
      pk.y = cvtpk(gelu_f(a2[mi][nj][2]+b4.z), gelu_f(a2[mi][nj][3]+b4.w));
      *(uint2*)&Hs[wv][tok][hb] = pk;
    }
  }
  f32x4 a3[2][8];
  #pragma unroll
  for (int mi=0;mi<2;mi++){
    s16x8 af = *(const s16x8*)&Hs[wv][mi*16+lc][lr*8];
    #pragma unroll
    for (int nj=0;nj<8;nj++){
      s16x8 b = *(const s16x8*)&W2T[(size_t)(nj*16+lc)*32 + lr*8];
      a3[mi][nj] = __builtin_amdgcn_mfma_f32_16x16x32_bf16(b, af, (f32x4){0.f,0.f,0.f,0.f}, 0,0,0);
    }
  }
  float sum[2]={0.f,0.f}, sq[2]={0.f,0.f};
  #pragma unroll
  for (int mi=0;mi<2;mi++){
    const int rl = rbase + mi*16 + lc;
    const size_t row = row0 + rl;
    #pragma unroll
    for (int nj=0;nj<8;nj++){
      const int colb = nj*16 + lr*4;
      float4 b4 = *(const float4*)&b2[colb];
      float4 r4 = *(const float4*)&res1[row*128 + colb];
      f32x4 v;
      v[0]=a3[mi][nj][0]+b4.x+r4.x; v[1]=a3[mi][nj][1]+b4.y+r4.y;
      v[2]=a3[mi][nj][2]+b4.z+r4.z; v[3]=a3[mi][nj][3]+b4.w+r4.w;
      if constexpr (SMODE==1){
        uint2 pu = *(const uint2*)&As[rl*128 + (((colb>>3) ^ (rl&7))*8) + (colb&7)];
        v[0] += bf2f((u16)(pu.x&0xffff)); v[1] += bf2f((u16)(pu.x>>16));
        v[2] += bf2f((u16)(pu.y&0xffff)); v[3] += bf2f((u16)(pu.y>>16));
      }
      float4 st; st.x=v[0]; st.y=v[1]; st.z=v[2]; st.w=v[3];
      *(float4*)&outp[row*128 + colb] = st;
      a3[mi][nj] = v;
      sum[mi] += (v[0]+v[1])+(v[2]+v[3]);
      sq[mi]  += (v[0]*v[0]+v[1]*v[1])+(v[2]*v[2]+v[3]*v[3]);
    }
  }
  #pragma unroll
  for (int mi=0;mi<2;mi++){
    float s2 = sum[mi], q2 = sq[mi];
    s2 += __shfl_xor(s2,16); s2 += __shfl_xor(s2,32);
    q2 += __shfl_xor(q2,16); q2 += __shfl_xor(q2,32);
    float mean = s2*(1.0f/128.0f);
    float var  = q2*(1.0f/128.0f) - mean*mean;
    float rs   = rsqrtf(var + 1e-5f);
    const size_t row = row0 + rbase + mi*16 + lc;
    #pragma unroll
    for (int nj=0;nj<8;nj++){
      const int colb = nj*16 + lr*4;
      float4 g4 = *(const float4*)&gn[colb];
      float4 h4 = *(const float4*)&gb[colb];
      uint2 pk;
      pk.x = cvtpk((a3[mi][nj][0]-mean)*rs*g4.x + h4.x,
                   (a3[mi][nj][1]-mean)*rs*g4.y + h4.y);
      pk.y = cvtpk((a3[mi][nj][2]-mean)*rs*g4.z + h4.z,
                   (a3[mi][nj][3]-mean)*rs*g4.w + h4.w);
      *(uint2*)&xnout[row*128 + colb] = pk;
    }
  }
}

// ======== Fused MLP v5: 64-token blocks (grid 1568), LDS 40KB -> 4 blocks/CU.
// Same dataflow as v4: As X-tile, Wb W1-chunk (64x128), Hb H (64x64), 8 chunks.
__global__ __launch_bounds__(256,4) void mlp_fused(
    const u16* __restrict__ X, const u16* __restrict__ W1T, const float* __restrict__ b1,
    const u16* __restrict__ W2T, const float* __restrict__ b2,
    const u16* __restrict__ A1T, const float* __restrict__ ab1,
    const u16* __restrict__ A2T, const float* __restrict__ ab2,
    float* __restrict__ outp)
{
  __shared__ u16 As[64*128];    // X, swizzled (staged once)
  __shared__ u16 Wb[64*128];    // W1 chunk (64 hid rows x 128 K), swizzled
  __shared__ u16 Hb[64*64];     // H (64 tok x 64 hid), slot-swizzled
  const int tid = threadIdx.x;
  const int wv = tid>>6, lane = tid&63, lr = lane>>4, lc = lane&15;
  const int wr = wv>>1, wc = wv&1;
  const size_t row0 = (size_t)blockIdx.x*64;

  stage_tileN<4>(X, row0, 128, 0, As, wv, lane);
  stage_tileN<4>(W1T, 0, 128, 0, Wb, wv, lane);
  __syncthreads();

  f32x4 oacc[2][4];
  #pragma unroll
  for (int mi=0;mi<2;mi++)
    #pragma unroll
    for (int nj=0;nj<4;nj++) oacc[mi][nj] = (f32x4){0.f,0.f,0.f,0.f};

  for (int ck=0; ck<8; ck++){
    if (ck > 0) __syncthreads();   // barA: drains W1[ck] stage; prev Hb reads done
    // ---- mlp1: acc = W1c x Xn -> D[hid@lr*4+r][tok@lc], 64 hid x 32 tok per wave ----
    f32x4 acc[2][2];
    #pragma unroll
    for (int mi=0;mi<2;mi++)
      #pragma unroll
      for (int nj=0;nj<2;nj++) acc[mi][nj] = (f32x4){0.f,0.f,0.f,0.f};
    #pragma unroll
    for (int kt=0; kt<4; kt++){
      s16x8 af[2], bfr[2];
      #pragma unroll
      for (int mi=0;mi<2;mi++)
        af[mi] = *(const s16x8*)&As[(wr*32+mi*16+lc)*128 + (((kt*4+lr) ^ (lc&7))*8)];
      #pragma unroll
      for (int nj=0;nj<2;nj++)
        bfr[nj] = *(const s16x8*)&Wb[(wc*32+nj*16+lc)*128 + (((kt*4+lr) ^ (lc&7))*8)];
      #pragma unroll
      for (int mi=0;mi<2;mi++)
        #pragma unroll
        for (int nj=0;nj<2;nj++)
          acc[mi][nj] = __builtin_amdgcn_mfma_f32_16x16x32_bf16(bfr[nj], af[mi], acc[mi][nj], 0,0,0);
    }
    // ---- H = gelu(acc+b1) -> Hb[tok][hid] ----
    #pragma unroll
    for (int nj=0;nj<2;nj++){
      const int hidb = wc*32 + nj*16 + lr*4;
      float4 b4 = *(const float4*)&b1[ck*64 + hidb];
      #pragma unroll
      for (int mi=0;mi<2;mi++){
        const int tok = wr*32 + mi*16 + lc;
        uint2 pk;
        pk.x = cvtpk(gelu_f(acc[mi][nj][0]+b4.x), gelu_f(acc[mi][nj][1]+b4.y));
        pk.y = cvtpk(gelu_f(acc[mi][nj][2]+b4.z), gelu_f(acc[mi][nj][3]+b4.w));
        *(uint2*)&Hb[tok*64 + (((hidb>>3) ^ (tok&7))*8) + (hidb&7)] = pk;
      }
    }
    __syncthreads();   // barC: H visible; all mlp1 Wb reads done
    if (ck < 7) stage_tileN<4>(W1T, (size_t)(ck+1)*64, 128, 0, Wb, wv, lane);  // drains at next barA
    // ---- mlp2 partial: oacc += H x W2c -> D[tok@lr*4+r][col@lc] ----
    #pragma unroll
    for (int kt=0; kt<2; kt++){
      s16x8 hf[2], wf[4];
      #pragma unroll
      for (int mi=0;mi<2;mi++){
        const int tok = wr*32 + mi*16 + lc;
        hf[mi] = *(const s16x8*)&Hb[tok*64 + (((kt*4+lr) ^ (tok&7))*8)];
      }
      #pragma unroll
      for (int nj=0;nj<4;nj++)
        wf[nj] = *(const s16x8*)&W2T[(size_t)(wc*64+nj*16+lc)*512 + ck*64 + kt*32 + lr*8];
      #pragma unroll
      for (int mi=0;mi<2;mi++)
        #pragma unroll
        for (int nj=0;nj<4;nj++)
          oacc[mi][nj] = __builtin_amdgcn_mfma_f32_16x16x32_bf16(hf[mi], wf[nj], oacc[mi][nj], 0,0,0);
    }
  }

  // ---- adapter1: a2 = A1 x Xn -> D[hid@lr*4+r][tok@lc], hid<32 (both wc redundant) ----
  f32x4 a2[2][2];
  #pragma unroll
  for (int mi=0;mi<2;mi++){ a2[mi][0]=(f32x4){0.f,0.f,0.f,0.f}; a2[mi][1]=(f32x4){0.f,0.f,0.f,0.f}; }
  #pragma unroll
  for (int kt=0; kt<4; kt++){
    s16x8 af[2];
    #pragma unroll
    for (int mi=0;mi<2;mi++)
      af[mi] = *(const s16x8*)&As[(wr*32+mi*16+lc)*128 + (((kt*4+lr) ^ (lc&7))*8)];
    s16x8 bA = *(const s16x8*)&A1T[(size_t)lc*128 + kt*32 + lr*8];
    s16x8 bB = *(const s16x8*)&A1T[(size_t)(16+lc)*128 + kt*32 + lr*8];
    #pragma unroll
    for (int mi=0;mi<2;mi++){
      a2[mi][0] = __builtin_amdgcn_mfma_f32_16x16x32_bf16(bA, af[mi], a2[mi][0], 0,0,0);
      a2[mi][1] = __builtin_amdgcn_mfma_f32_16x16x32_bf16(bB, af[mi], a2[mi][1], 0,0,0);
    }
  }
  __syncthreads();   // all Xn reads of As done; last chunk's Hb reads done
  // ---- Hq (x0.5 folded) -> As[tok*64 + swz(hid)] (16B-aligned slots) ----
  if (wc==0){
    #pragma unroll
    for (int nj=0;nj<2;nj++){
      const int hb = nj*16 + lr*4;
      float4 b4 = *(const float4*)&ab1[hb];
      #pragma unroll
      for (int mi=0;mi<2;mi++){
        const int tok = wr*32 + mi*16 + lc;
        uint2 pk;
        pk.x = cvtpk(0.5f*gelu_f(a2[mi][nj][0]+b4.x), 0.5f*gelu_f(a2[mi][nj][1]+b4.y));
        pk.y = cvtpk(0.5f*gelu_f(a2[mi][nj][2]+b4.z), 0.5f*gelu_f(a2[mi][nj][3]+b4.w));
        *(uint2*)&As[tok*64 + (((hb>>3) ^ (tok&7))*8) + (hb&7)] = pk;
      }
    }
  }
  __syncthreads();
  // ---- adapter2: oacc += Hq x A2 (K=32, one mfma per tile) ----
  {
    s16x8 hqf[2];
    #pragma unroll
    for (int mi=0;mi<2;mi++){
      const int tok = wr*32 + mi*16 + lc;
      hqf[mi] = *(const s16x8*)&As[tok*64 + ((lr ^ (tok&7))*8)];
    }
    #pragma unroll
    for (int nj=0;nj<4;nj++){
      s16x8 a2f = *(const s16x8*)&A2T[(size_t)(wc*64+nj*16+lc)*32 + lr*8];
      #pragma unroll
      for (int mi=0;mi<2;mi++)
        oacc[mi][nj] = __builtin_amdgcn_mfma_f32_16x16x32_bf16(hqf[mi], a2f, oacc[mi][nj], 0,0,0);
    }
  }
  // ---- epilogue: out += oacc + b2 + 0.5*ab2 (64B-coalesced scalar f32 RMW) ----
  #pragma unroll
  for (int nj=0;nj<4;nj++){
    const int col = wc*64 + nj*16 + lc;
    const float badd = b2[col] + 0.5f*ab2[col];
    #pragma unroll
    for (int mi=0;mi<2;mi++){
      #pragma unroll
      for (int r=0;r<4;r++){
        const size_t row = row0 + wr*32 + mi*16 + lr*4 + r;
        outp[row*128 + col] += oacc[mi][nj][r] + badd;
      }
    }
  }
}

// ---------------- temporal attention (T=8 per (b,l), 4 heads), bf16 out ----------------
__global__ __launch_bounds__(256) void t_attn_kernel(const u16* __restrict__ qkv,
    const float* __restrict__ tpb, u16* __restrict__ o)
{
  const int tid = threadIdx.x;
  const int li = tid>>5, h = (tid>>3)&3, t = tid&7;
  const int b = blockIdx.x/392, lt = blockIdx.x%392;
  const int l = lt*8+li;
  const size_t rowt = (size_t)(b*8+t)*LDIM + l;
  const u16* qp = qkv + rowt*384 + h*32;
  f32x8 q0 = ldbf8(qp)   *SCALE_F, q1 = ldbf8(qp+8) *SCALE_F,
        q2 = ldbf8(qp+16)*SCALE_F, q3 = ldbf8(qp+24)*SCALE_F;
  float s[8];
  #pragma unroll
  for (int t2=0;t2<8;t2++){
    const u16* kp = qkv + ((size_t)(b*8+t2)*LDIM + l)*384 + 128 + h*32;
    f32x8 d = q0*ldbf8(kp) + q1*ldbf8(kp+8) + q2*ldbf8(kp+16) + q3*ldbf8(kp+24);
    s[t2] = sum8(d) + tpb[(t-t2+7)*4 + h];
  }
  float m = s[0];
  #pragma unroll
  for (int t2=1;t2<8;t2++) m = fmaxf(m, s[t2]);
  float ssum = 0.f;
  #pragma unroll
  for (int t2=0;t2<8;t2++){ s[t2] = __expf(s[t2]-m); ssum += s[t2]; }
  const float inv = 1.0f/ssum;
  f32x8 o0={0,0,0,0,0,0,0,0}, o1={0,0,0,0,0,0,0,0},
        o2={0,0,0,0,0,0,0,0}, o3={0,0,0,0,0,0,0,0};
  #pragma unroll
  for (int t2=0;t2<8;t2++){
    const u16* vp = qkv + ((size_t)(b*8+t2)*LDIM + l)*384 + 256 + h*32;
    float aw = s[t2]*inv;
    o0 += aw*ldbf8(vp); o1 += aw*ldbf8(vp+8); o2 += aw*ldbf8(vp+16); o3 += aw*ldbf8(vp+24);
  }
  u16* op = o + rowt*128 + h*32;
  *(u16x8*)op      = pack8(o0); *(u16x8*)(op+8)  = pack8(o1);
  *(u16x8*)(op+16) = pack8(o2); *(u16x8*)(op+24) = pack8(o3);
}

// --------- MFMA shifted-window spatial attention ---------
__global__ __launch_bounds__(256,2) void s_attn_mfma(const u16* __restrict__ qkv,
    const float* __restrict__ rpb, u16* __restrict__ o)
{
  __shared__ u16 Qs[64][136];
  __shared__ u16 Ks[64][136];
  __shared__ u16 Vt[128][72];
  __shared__ float rpbL[676];
  __shared__ int rowL[49];
  __shared__ int codeL[49];
  const int tid = threadIdx.x;
  const int bidx = blockIdx.x;
  const int bt = bidx>>6, wh = (bidx>>3)&7, ww = bidx&7;
  if (tid < 49){
    int ph = tid/7, pwv = tid%7;
    int rh = wh*7+ph, rw = ww*7+pwv;
    int oh = rh+3; if (oh>=56) oh-=56;   // roll(-3)
    int ow = rw+3; if (ow>=56) ow-=56;
    rowL[tid] = bt*LDIM + oh*56 + ow;
    codeL[tid] = ((rh<49)?0:((rh<53)?1:2))*3 + ((rw<49)?0:((rw<53)?1:2));
  }
  for (int i2 = tid; i2 < 676; i2 += 256) rpbL[i2] = rpb[i2];
  for (int idx = tid; idx < 128*15; idx += 256){
    int d = idx/15, jj = 49 + (idx - d*15);
    Vt[d][jj] = 0;
  }
  __syncthreads();
  #pragma unroll
  for (int it = 0; it < 10; it++){
    int idx = it*256 + tid;
    if (idx < 2352){
      int j = idx/48, s = idx - j*48;
      const u16* src = qkv + (size_t)rowL[j]*384 + s*8;
      u16x8 v = *(const u16x8*)src;
      if (s < 16)      *(u16x8*)&Qs[j][s*8] = v;
      else if (s < 32) *(u16x8*)&Ks[j][(s-16)*8] = v;
      else { int c0 = (s-32)*8;
        #pragma unroll
        for (int e=0;e<8;e++) Vt[c0+e][j] = v[e];
      }
    }
  }
  __syncthreads();

  const int h = tid>>6, lane = tid&63, lr = lane>>4, lc = lane&15;
  s16x8 qf[4], kf[4];
  #pragma unroll
  for (int t=0;t<4;t++){
    qf[t] = *(const s16x8*)&Qs[t*16+lc][h*32+lr*8];
    kf[t] = *(const s16x8*)&Ks[t*16+lc][h*32+lr*8];
  }
  f32x4 sa[4][4];
  #pragma unroll
  for (int tj=0;tj<4;tj++){
    #pragma unroll
    for (int ti=0;ti<4;ti++)
      sa[tj][ti] = __builtin_amdgcn_mfma_f32_16x16x32_bf16(kf[tj], qf[ti], (f32x4){0.f,0.f,0.f,0.f}, 0,0,0);
  }
  int ihv[4], iwv[4], civ[4];
  #pragma unroll
  for (int ti=0;ti<4;ti++){
    int i = ti*16+lc; int im = (i<49)? i:48;
    int ih2 = (im*147)>>10; ihv[ti]=ih2; iwv[ti]=im-ih2*7; civ[ti]=codeL[im];
  }
  float rs[4] = {0.f,0.f,0.f,0.f};
  #pragma unroll
  for (int tj=0;tj<4;tj++){
    #pragma unroll
    for (int r=0;r<4;r++){
      int j = tj*16 + lr*4 + r;
      bool jv = (j<49);
      int jm = jv? j:48;
      int jh2 = (jm*147)>>10; int jw2 = jm - jh2*7; int cj = codeL[jm];
      #pragma unroll
      for (int ti=0;ti<4;ti++){
        float sv = sa[tj][ti][r]*SCALE_F
                 + rpbL[((ihv[ti]-jh2+6)*13 + (iwv[ti]-jw2+6))*4 + h];
        if (civ[ti] != cj) sv -= 100.f;
        float pv = jv ? __expf(sv) : 0.f;
        sa[tj][ti][r] = pv;
        rs[ti] += pv;
      }
    }
  }
  #pragma unroll
  for (int ti=0;ti<4;ti++){
    float t2 = rs[ti];
    t2 += __shfl_xor(t2, 16);
    t2 += __shfl_xor(t2, 32);
    rs[ti] = 1.0f/t2;
  }
  unsigned lo[4][4], hi[4][4];
  #pragma unroll
  for (int tj=0;tj<4;tj++){
    #pragma unroll
    for (int ti=0;ti<4;ti++){
      float inv = rs[ti];
      lo[tj][ti] = cvtpk(sa[tj][ti][0]*inv, sa[tj][ti][1]*inv);
      hi[tj][ti] = cvtpk(sa[tj][ti][2]*inv, sa[tj][ti][3]*inv);
    }
  }
  f32x4 oa[4][2];
  #pragma unroll
  for (int mi=0;mi<4;mi++){ oa[mi][0]=(f32x4){0.f,0.f,0.f,0.f}; oa[mi][1]=(f32x4){0.f,0.f,0.f,0.f}; }
  const int srcA = lc + ((lane>>4)&1)*32;
  const int srcB = srcA + 16;
  const bool hiHalf = (lr>=2);
  #pragma unroll
  for (int kt=0;kt<2;kt++){
    s16x8 vf[2];
    #pragma unroll
    for (int nd=0;nd<2;nd++)
      vf[nd] = *(const s16x8*)&Vt[h*32 + nd*16 + lc][kt*32 + lr*8];
    #pragma unroll
    for (int mi=0;mi<4;mi++){
      unsigned wA0 = __shfl(lo[2*kt][mi],   srcA), wB0 = __shfl(lo[2*kt+1][mi], srcA);
      unsigned wA1 = __shfl(hi[2*kt][mi],   srcA), wB1 = __shfl(hi[2*kt+1][mi], srcA);
      unsigned wA2 = __shfl(lo[2*kt][mi],   srcB), wB2 = __shfl(lo[2*kt+1][mi], srcB);
      unsigned wA3 = __shfl(hi[2*kt][mi],   srcB), wB3 = __shfl(hi[2*kt+1][mi], srcB);
      union { unsigned u[4]; s16x8 v8; } cv;
      cv.u[0] = hiHalf? wB0 : wA0;
      cv.u[1] = hiHalf? wB1 : wA1;
      cv.u[2] = hiHalf? wB2 : wA2;
      cv.u[3] = hiHalf? wB3 : wA3;
      #pragma unroll
      for (int nd=0;nd<2;nd++)
        oa[mi][nd] = __builtin_amdgcn_mfma_f32_16x16x32_bf16(cv.v8, vf[nd], oa[mi][nd], 0,0,0);
    }
  }
  #pragma unroll
  for (int mi=0;mi<4;mi++){
    #pragma unroll
    for (int r=0;r<4;r++){
      int i = mi*16 + lr*4 + r;
      if (i < 49){
        size_t orow = (size_t)rowL[i]*128 + h*32;
        o[orow + lc]      = f2bf(oa[mi][0][r]);
        o[orow + 16 + lc] = f2bf(oa[mi][1][r]);
      }
    }
  }
}

extern "C" void kernel_launch(void* const* d_in, const int* in_sizes, int n_in,
                              void* d_out, int out_size, void* d_ws, size_t ws_size,
                              hipStream_t stream)
{
  (void)in_sizes; (void)n_in; (void)out_size; (void)ws_size;
  const float* x      = (const float*)d_in[0];
  const float* qkv_w  = (const float*)d_in[1];
  const float* qkv_b  = (const float*)d_in[2];
  const float* proj_w = (const float*)d_in[3];
  const float* proj_b = (const float*)d_in[4];
  const float* rpb    = (const float*)d_in[5];
  const float* tpb    = (const float*)d_in[6];
  const float* n1g    = (const float*)d_in[7];
  const float* n1b    = (const float*)d_in[8];
  const float* n2g    = (const float*)d_in[9];
  const float* n2b    = (const float*)d_in[10];
  const float* mw1    = (const float*)d_in[11];
  const float* mb1    = (const float*)d_in[12];
  const float* mw2    = (const float*)d_in[13];
  const float* mb2    = (const float*)d_in[14];
  const float* sw1    = (const float*)d_in[15];
  const float* sb1    = (const float*)d_in[16];
  const float* sw2    = (const float*)d_in[17];
  const float* sb2    = (const float*)d_in[18];
  const float* tw1    = (const float*)d_in[19];
  const float* tb1    = (const float*)d_in[20];
  const float* tw2    = (const float*)d_in[21];
  const float* tb2    = (const float*)d_in[22];
  const float* aw1    = (const float*)d_in[23];
  const float* ab1    = (const float*)d_in[24];
  const float* aw2    = (const float*)d_in[25];
  const float* ab2    = (const float*)d_in[26];

  char* ws = (char*)d_ws;
  u16*   Xn  = (u16*)(ws);
  u16*   QKV = (u16*)(ws + 25690112ULL);
  u16*   O   = (u16*)(ws + 102760448ULL);
  float* Cb  = (float*)(ws + 134873088ULL);
  u16*   WT  = (u16*)(ws + 186253312ULL);
  float* out = (float*)d_out;

  const u16 *WTqkv=WT, *WTproj=WT+49152, *WTm1=WT+65536, *WTm2=WT+131072,
            *WTt1=WT+196608, *WTt2=WT+200704, *WTs1=WT+204800, *WTs2=WT+208896,
            *WTa1=WT+212992, *WTa2=WT+217088;

  WSrc srcs; srcs.p[0]=qkv_w; srcs.p[1]=proj_w; srcs.p[2]=mw1; srcs.p[3]=mw2;
  srcs.p[4]=tw1; srcs.p[5]=tw2; srcs.p[6]=sw1; srcs.p[7]=sw2; srcs.p[8]=aw1; srcs.p[9]=aw2;
  prep_w<<<864,256,0,stream>>>(srcs, WT);

  // ---- temporal attention + T_Adapter (+fused LN of its output) ----
  ln_kernel<<<25088,256,0,stream>>>(x, n1g, n1b, Xn);
  gemm_tile<1,3,0><<<784,256,0,stream>>>(Xn, WTqkv, qkv_b, QKV, 384, nullptr,nullptr);
  t_attn_kernel<<<1568,256,0,stream>>>(QKV, tpb, O);
  proj_ada_tile<0><<<784,256,0,stream>>>(O, WTproj, proj_b, WTt1, tb1, WTt2, tb2,
                                          x, Cb, n1g, n1b, Xn);
  // ---- shifted-window spatial attention + S_Adapter (+fused LN2) ----
  gemm_tile<1,3,0><<<784,256,0,stream>>>(Xn, WTqkv, qkv_b, QKV, 384, nullptr,nullptr);
  s_attn_mfma<<<2048,256,0,stream>>>(QKV, rpb, O);
  proj_ada_tile<1><<<784,256,0,stream>>>(O, WTproj, proj_b, WTs1, sb1, WTs2, sb2,
                                          Cb, out, n2g, n2b, Xn);
  // ---- fully fused MLP + MLP_Adapter (v5: 64-token blocks, 4 blocks/CU) ----
  mlp_fused<<<1568,256,0,stream>>>(Xn, WTm1, mb1, WTm2, mb2, WTa1, ab1, WTa2, ab2, out);
}

// Round 17
// 375.793 us; speedup vs baseline: 1.0030x; 1.0030x over previous
//
#include <hip/hip_runtime.h>

#define TOKS 100352   // BT*L = 32*3136
#define LDIM 3136     // H*W
#define SCALE_F 0.17677669529663687f  // 32^-0.5

typedef unsigned short u16;
typedef u16   u16x8 __attribute__((ext_vector_type(8)));
typedef short s16x8 __attribute__((ext_vector_type(8)));
typedef float f32x8 __attribute__((ext_vector_type(8)));
typedef float f32x4 __attribute__((ext_vector_type(4)));

__device__ __forceinline__ float bf2f(u16 u){ return __uint_as_float(((unsigned)u)<<16); }
__device__ __forceinline__ u16 f2bf(float f){
  unsigned u = __float_as_uint(f);
  return (u16)((u + 0x7FFFu + ((u>>16)&1u)) >> 16);   // RNE
}
// packed bf16 convert: lo=cvt(a), hi=cvt(b)  (RNE) — single VALU instr
__device__ __forceinline__ unsigned cvtpk(float a, float b){
  unsigned r;
  asm("v_cvt_pk_bf16_f32 %0, %1, %2" : "=v"(r) : "v"(a), "v"(b));
  return r;
}
__device__ __forceinline__ f32x8 ldbf8(const u16* p){
  u16x8 u = *(const u16x8*)p;
  f32x8 f;
  #pragma unroll
  for (int j=0;j<8;j++) f[j] = bf2f(u[j]);
  return f;
}
__device__ __forceinline__ u16x8 pack8(f32x8 v){
  u16x8 r;
  #pragma unroll
  for (int j=0;j<8;j++) r[j] = f2bf(v[j]);
  return r;
}
__device__ __forceinline__ float sum8(f32x8 a){
  return ((a[0]+a[1])+(a[2]+a[3]))+((a[4]+a[5])+(a[6]+a[7]));
}
// sigmoid-form gelu: x*sigmoid(1.702x). |err| <~0.005 for |x|<1 (our pre-act range)
__device__ __forceinline__ float gelu_f(float x){
  return x / (1.0f + __expf(-1.702f*x));
}

// ---- async global->LDS, 16B per lane; LDS dest = wave-uniform base + lane*16 ----
__device__ __forceinline__ void gl16(const u16* g, u16* l){
  __builtin_amdgcn_global_load_lds(
      (const __attribute__((address_space(1))) unsigned*)(const void*)g,
      (__attribute__((address_space(3))) unsigned*)(void*)l, 16, 0, 0);
}
// stage ROWS x 128 bf16 tile into XOR-swizzled LDS (slot = kb ^ (r&7)) via
// pre-swizzled per-lane SOURCE (rule: linear dest + inverse-swz source + swz read).
template<int ITERS>
__device__ __forceinline__ void stage_tileN(const u16* __restrict__ src, size_t rowstart,
    int KTOT, int koff, u16* lds, int wv, int lane){
  const int rr = wv*4 + (lane>>4);
  const int sl = lane&15;
  const int kb = sl ^ (rr&7);
  const u16* g0 = src + (rowstart + rr)*(size_t)KTOT + koff + kb*8;
  u16* l0 = lds + wv*4*128;
  #pragma unroll
  for (int it=0; it<ITERS; it++)
    gl16(g0 + (size_t)it*16*KTOT, l0 + it*16*128);
}
__device__ __forceinline__ void stage_tile(const u16* __restrict__ src, size_t rowstart,
    int KTOT, int koff, u16* lds, int wv, int lane){
  stage_tileN<8>(src, rowstart, KTOT, koff, lds, wv, lane);
}

// ---------------- weight prep: f32 (K,N) -> bf16 transposed (N,K) ----------------
struct WSrc { const float* p[10]; };
__global__ __launch_bounds__(256) void prep_w(WSrc s, u16* __restrict__ dst){
  const int Ks[10]={128,128,128,512,128,32,128,32,128,32};
  const int Ns[10]={384,128,512,128,32,128,32,128,32,128};
  const int off[11]={0,49152,65536,131072,196608,200704,204800,208896,212992,217088,221184};
  int idx = blockIdx.x*256+threadIdx.x;
  int m=0;
  #pragma unroll
  for (int i=0;i<10;i++) if (idx>=off[i+1]) m=i+1;
  int e = idx-off[m];
  int K=Ks[m], Nn=Ns[m];
  int n=e/K, k=e-n*K;
  dst[idx] = f2bf(s.p[m][k*Nn+n]);
}

// ---------------- LayerNorm: one wave per token (C=128), bf16 out ----------------
__global__ __launch_bounds__(256) void ln_kernel(const float* __restrict__ x,
    const float* __restrict__ g, const float* __restrict__ bta, u16* __restrict__ out)
{
  int tok  = (int)((blockIdx.x*256u + threadIdx.x) >> 6);
  int lane = threadIdx.x & 63;
  const float* xr = x + (size_t)tok*128;
  float v0 = xr[lane], v1 = xr[lane+64];
  float s = v0+v1;
  #pragma unroll
  for (int o=32;o;o>>=1) s += __shfl_xor(s,o);
  float m = s*(1.0f/128.0f);
  float d0=v0-m, d1=v1-m;
  float q = d0*d0+d1*d1;
  #pragma unroll
  for (int o=32;o;o>>=1) q += __shfl_xor(q,o);
  float rs = rsqrtf(q*(1.0f/128.0f)+1e-5f);
  u16* orow = out + (size_t)tok*128;
  orow[lane]    = f2bf(d0*rs*g[lane]   + bta[lane]);
  orow[lane+64] = f2bf(d1*rs*g[lane+64]+ bta[lane+64]);
}

// ======== Tiled MFMA GEMM, SWAPPED operands: D[col @ lr*4+r][row @ lc] ========
// EPI: 0 = bf16 bias (direct uint2 stores); 1 = + gelu
template<int KCH, int NTC, int EPI>
__global__ __launch_bounds__(256,2) void gemm_tile(
    const u16* __restrict__ X, const u16* __restrict__ WT,
    const float* __restrict__ bias, void* outp, int N,
    const float* res1, const u16* __restrict__ adab)
{
  constexpr int KTOT = KCH*128;
  __shared__ u16 As[128*128];
  __shared__ u16 Bs[128*128];
  const int tid = threadIdx.x;
  const int wv = tid>>6, lane = tid&63, lr = lane>>4, lc = lane&15;
  const int wr = wv>>1, wc = wv&1;
  const size_t row0 = (size_t)blockIdx.x*128;

  f32x4 acc[4][4];
  #pragma unroll
  for (int mi=0;mi<4;mi++)
    #pragma unroll
    for (int nj=0;nj<4;nj++) acc[mi][nj] = (f32x4){0.f,0.f,0.f,0.f};

  for (int kc=0; kc<KCH; kc++){
    for (int nt=0; nt<NTC; nt++){
      if (kc+nt > 0) __syncthreads();
      if (nt == 0) stage_tile(X, row0, KTOT, kc*128, As, wv, lane);
      stage_tile(WT, (size_t)nt*128, KTOT, kc*128, Bs, wv, lane);
      __syncthreads();
      #pragma unroll
      for (int kt=0; kt<4; kt++){
        s16x8 af[4], bfr[4];
        #pragma unroll
        for (int mi=0;mi<4;mi++){
          int row = wr*64 + mi*16 + lc;
          af[mi] = *(const s16x8*)&As[row*128 + (((kt*4+lr) ^ (lc&7))*8)];
        }
        #pragma unroll
        for (int nj=0;nj<4;nj++){
          int col = wc*64 + nj*16 + lc;
          bfr[nj] = *(const s16x8*)&Bs[col*128 + (((kt*4+lr) ^ (lc&7))*8)];
        }
        #pragma unroll
        for (int mi=0;mi<4;mi++)
          #pragma unroll
          for (int nj=0;nj<4;nj++)
            acc[mi][nj] = __builtin_amdgcn_mfma_f32_16x16x32_bf16(bfr[nj], af[mi], acc[mi][nj], 0,0,0);
      }
      {
        #pragma unroll
        for (int nj=0;nj<4;nj++){
          const int colb = nt*128 + wc*64 + nj*16 + lr*4;
          float4 b4 = *(const float4*)&bias[colb];
          #pragma unroll
          for (int mi=0;mi<4;mi++){
            const size_t row = row0 + wr*64 + mi*16 + lc;
            float v0=acc[mi][nj][0]+b4.x, v1=acc[mi][nj][1]+b4.y,
                  v2=acc[mi][nj][2]+b4.z, v3=acc[mi][nj][3]+b4.w;
            if constexpr (EPI==1){ v0=gelu_f(v0); v1=gelu_f(v1); v2=gelu_f(v2); v3=gelu_f(v3); }
            uint2 pk; pk.x = cvtpk(v0,v1); pk.y = cvtpk(v2,v3);
            *(uint2*)&((u16*)outp)[row*(size_t)N + colb] = pk;
            acc[mi][nj] = (f32x4){0.f,0.f,0.f,0.f};
          }
        }
      }
    }
  }
  (void)res1; (void)adab;
}

// ======== Fused proj + adapter + residual + LayerNorm (row-local) ========
template<int SMODE>
__global__ __launch_bounds__(256,2) void proj_ada_tile(
    const u16* __restrict__ O, const u16* __restrict__ PW, const float* __restrict__ pb,
    const u16* __restrict__ W1T, const float* __restrict__ b1,
    const u16* __restrict__ W2T, const float* __restrict__ b2,
    const float* __restrict__ res1, float* __restrict__ outp,
    const float* __restrict__ gn, const float* __restrict__ gb, u16* __restrict__ xnout)
{
  __shared__ u16 As[128*128];
  __shared__ u16 Bs[128*128];
  __shared__ u16 Hs[4][32][40];
  const int tid = threadIdx.x;
  const int wv = tid>>6, lane = tid&63, lr = lane>>4, lc = lane&15;
  const int wr = wv>>1, wc = wv&1;
  const size_t row0 = (size_t)blockIdx.x*128;
  stage_tile(O, row0, 128, 0, As, wv, lane);
  stage_tile(PW, 0, 128, 0, Bs, wv, lane);
  __syncthreads();
  f32x4 acc[4][4];
  #pragma unroll
  for (int mi=0;mi<4;mi++)
    #pragma unroll
    for (int nj=0;nj<4;nj++) acc[mi][nj] = (f32x4){0.f,0.f,0.f,0.f};
  #pragma unroll
  for (int kt=0; kt<4; kt++){
    s16x8 af[4], bfr[4];
    #pragma unroll
    for (int mi=0;mi<4;mi++)
      af[mi] = *(const s16x8*)&As[(wr*64+mi*16+lc)*128 + (((kt*4+lr) ^ (lc&7))*8)];
    #pragma unroll
    for (int nj=0;nj<4;nj++)
      bfr[nj] = *(const s16x8*)&Bs[(wc*64+nj*16+lc)*128 + (((kt*4+lr) ^ (lc&7))*8)];
    #pragma unroll
    for (int mi=0;mi<4;mi++)
      #pragma unroll
      for (int nj=0;nj<4;nj++)
        acc[mi][nj] = __builtin_amdgcn_mfma_f32_16x16x32_bf16(bfr[nj], af[mi], acc[mi][nj], 0,0,0);
  }
  __syncthreads();
  #pragma unroll
  for (int nj=0;nj<4;nj++){
    const int colb = wc*64 + nj*16 + lr*4;
    float4 b4 = *(const float4*)&pb[colb];
    #pragma unroll
    for (int mi=0;mi<4;mi++){
      const int row = wr*64 + mi*16 + lc;
      uint2 pk;
      pk.x = cvtpk(acc[mi][nj][0]+b4.x, acc[mi][nj][1]+b4.y);
      pk.y = cvtpk(acc[mi][nj][2]+b4.z, acc[mi][nj][3]+b4.w);
      *(uint2*)&As[row*128 + (((colb>>3) ^ (row&7))*8) + (colb&7)] = pk;
    }
  }
  __syncthreads();
  const int rbase = wv*32;
  f32x4 a2[2][2];
  #pragma unroll
  for (int mi=0;mi<2;mi++){ a2[mi][0]=(f32x4){0.f,0.f,0.f,0.f}; a2[mi][1]=(f32x4){0.f,0.f,0.f,0.f}; }
  #pragma unroll
  for (int kt=0; kt<4; kt++){
    s16x8 af0 = *(const s16x8*)&As[(rbase+lc)*128 + (((kt*4+lr) ^ (lc&7))*8)];
    s16x8 af1 = *(const s16x8*)&As[(rbase+16+lc)*128 + (((kt*4+lr) ^ (lc&7))*8)];
    #pragma unroll
    for (int nj=0; nj<2; nj++){
      s16x8 b = *(const s16x8*)&W1T[(size_t)(nj*16+lc)*128 + kt*32 + lr*8];
      a2[0][nj] = __builtin_amdgcn_mfma_f32_16x16x32_bf16(b, af0, a2[0][nj], 0,0,0);
      a2[1][nj] = __builtin_amdgcn_mfma_f32_16x16x32_bf16(b, af1, a2[1][nj], 0,0,0);
    }
  }
  #pragma unroll
  for (int nj=0;nj<2;nj++){
    const int hb = nj*16 + lr*4;
    float4 b4 = *(const float4*)&b1[hb];
    #pragma unroll
    for (int mi=0;mi<2;mi++){
      const int tok = mi*16 + lc;
      uint2 pk;
      pk.x = cvtpk(gelu_f(a2[mi][nj][0]+b4.x), gelu_f(a2[mi][nj][1]+b4.y));
      pk.y = cvtpk(gelu_f(a2[mi][nj][2]+b4.z), gelu_f(a2[mi][nj][3]+b4.w));
      *(uint2*)&Hs[wv][tok][hb] = pk;
    }
  }
  f32x4 a3[2][8];
  #pragma unroll
  for (int mi=0;mi<2;mi++){
    s16x8 af = *(const s16x8*)&Hs[wv][mi*16+lc][lr*8];
    #pragma unroll
    for (int nj=0;nj<8;nj++){
      s16x8 b = *(const s16x8*)&W2T[(size_t)(nj*16+lc)*32 + lr*8];
      a3[mi][nj] = __builtin_amdgcn_mfma_f32_16x16x32_bf16(b, af, (f32x4){0.f,0.f,0.f,0.f}, 0,0,0);
    }
  }
  float sum[2]={0.f,0.f}, sq[2]={0.f,0.f};
  #pragma unroll
  for (int mi=0;mi<2;mi++){
    const int rl = rbase + mi*16 + lc;
    const size_t row = row0 + rl;
    #pragma unroll
    for (int nj=0;nj<8;nj++){
      const int colb = nj*16 + lr*4;
      float4 b4 = *(const float4*)&b2[colb];
      float4 r4 = *(const float4*)&res1[row*128 + colb];
      f32x4 v;
      v[0]=a3[mi][nj][0]+b4.x+r4.x; v[1]=a3[mi][nj][1]+b4.y+r4.y;
      v[2]=a3[mi][nj][2]+b4.z+r4.z; v[3]=a3[mi][nj][3]+b4.w+r4.w;
      if constexpr (SMODE==1){
        uint2 pu = *(const uint2*)&As[rl*128 + (((colb>>3) ^ (rl&7))*8) + (colb&7)];
        v[0] += bf2f((u16)(pu.x&0xffff)); v[1] += bf2f((u16)(pu.x>>16));
        v[2] += bf2f((u16)(pu.y&0xffff)); v[3] += bf2f((u16)(pu.y>>16));
      }
      float4 st; st.x=v[0]; st.y=v[1]; st.z=v[2]; st.w=v[3];
      *(float4*)&outp[row*128 + colb] = st;
      a3[mi][nj] = v;
      sum[mi] += (v[0]+v[1])+(v[2]+v[3]);
      sq[mi]  += (v[0]*v[0]+v[1]*v[1])+(v[2]*v[2]+v[3]*v[3]);
    }
  }
  #pragma unroll
  for (int mi=0;mi<2;mi++){
    float s2 = sum[mi], q2 = sq[mi];
    s2 += __shfl_xor(s2,16); s2 += __shfl_xor(s2,32);
    q2 += __shfl_xor(q2,16); q2 += __shfl_xor(q2,32);
    float mean = s2*(1.0f/128.0f);
    float var  = q2*(1.0f/128.0f) - mean*mean;
    float rs   = rsqrtf(var + 1e-5f);
    const size_t row = row0 + rbase + mi*16 + lc;
    #pragma unroll
    for (int nj=0;nj<8;nj++){
      const int colb = nj*16 + lr*4;
      float4 g4 = *(const float4*)&gn[colb];
      float4 h4 = *(const float4*)&gb[colb];
      uint2 pk;
      pk.x = cvtpk((a3[mi][nj][0]-mean)*rs*g4.x + h4.x,
                   (a3[mi][nj][1]-mean)*rs*g4.y + h4.y);
      pk.y = cvtpk((a3[mi][nj][2]-mean)*rs*g4.z + h4.z,
                   (a3[mi][nj][3]-mean)*rs*g4.w + h4.w);
      *(uint2*)&xnout[row*128 + colb] = pk;
    }
  }
}

// ======== Fused MLP v4: separate 16KB W1-chunk + 16KB H buffers, 64-hid chunks.
// Next W1 stage issued AFTER the H-visibility barrier -> drains under mlp2 at the
// next loop-top barrier (no dead stage window).
__global__ __launch_bounds__(256,2) void mlp_fused(
    const u16* __restrict__ X, const u16* __restrict__ W1T, const float* __restrict__ b1,
    const u16* __restrict__ W2T, const float* __restrict__ b2,
    const u16* __restrict__ A1T, const float* __restrict__ ab1,
    const u16* __restrict__ A2T, const float* __restrict__ ab2,
    float* __restrict__ outp)
{
  __shared__ u16 As[128*128];   // X, swizzled (staged once)
  __shared__ u16 Wb[64*128];    // W1 chunk (64 hid rows x 128 K), swizzled
  __shared__ u16 Hb[128*64];    // H (128 tok x 64 hid), slot-swizzled
  const int tid = threadIdx.x;
  const int wv = tid>>6, lane = tid&63, lr = lane>>4, lc = lane&15;
  const int wr = wv>>1, wc = wv&1;
  const size_t row0 = (size_t)blockIdx.x*128;

  stage_tile(X, row0, 128, 0, As, wv, lane);
  stage_tileN<4>(W1T, 0, 128, 0, Wb, wv, lane);
  __syncthreads();

  f32x4 oacc[4][4];
  #pragma unroll
  for (int mi=0;mi<4;mi++)
    #pragma unroll
    for (int nj=0;nj<4;nj++) oacc[mi][nj] = (f32x4){0.f,0.f,0.f,0.f};

  for (int ck=0; ck<8; ck++){
    if (ck > 0) __syncthreads();   // barA: drains W1[ck] stage; prev Hb reads done
    // ---- mlp1: acc = W1c x Xn -> D[hid@lr*4+r][tok@lc], 64 hid ----
    f32x4 acc[4][2];
    #pragma unroll
    for (int mi=0;mi<4;mi++)
      #pragma unroll
      for (int nj=0;nj<2;nj++) acc[mi][nj] = (f32x4){0.f,0.f,0.f,0.f};
    #pragma unroll
    for (int kt=0; kt<4; kt++){
      s16x8 af[4], bfr[2];
      #pragma unroll
      for (int mi=0;mi<4;mi++)
        af[mi] = *(const s16x8*)&As[(wr*64+mi*16+lc)*128 + (((kt*4+lr) ^ (lc&7))*8)];
      #pragma unroll
      for (int nj=0;nj<2;nj++)
        bfr[nj] = *(const s16x8*)&Wb[(wc*32+nj*16+lc)*128 + (((kt*4+lr) ^ (lc&7))*8)];
      #pragma unroll
      for (int mi=0;mi<4;mi++)
        #pragma unroll
        for (int nj=0;nj<2;nj++)
          acc[mi][nj] = __builtin_amdgcn_mfma_f32_16x16x32_bf16(bfr[nj], af[mi], acc[mi][nj], 0,0,0);
    }
    // ---- H = gelu(acc+b1) -> Hb[tok][hid] (prev chunk's Hb reads done before barA) ----
    #pragma unroll
    for (int nj=0;nj<2;nj++){
      const int hidb = wc*32 + nj*16 + lr*4;
      float4 b4 = *(const float4*)&b1[ck*64 + hidb];
      #pragma unroll
      for (int mi=0;mi<4;mi++){
        const int tok = wr*64 + mi*16 + lc;
        uint2 pk;
        pk.x = cvtpk(gelu_f(acc[mi][nj][0]+b4.x), gelu_f(acc[mi][nj][1]+b4.y));
        pk.y = cvtpk(gelu_f(acc[mi][nj][2]+b4.z), gelu_f(acc[mi][nj][3]+b4.w));
        *(uint2*)&Hb[tok*64 + (((hidb>>3) ^ (tok&7))*8) + (hidb&7)] = pk;
      }
    }
    __syncthreads();   // barC: H visible; all mlp1 Wb reads done
    if (ck < 7) stage_tileN<4>(W1T, (size_t)(ck+1)*64, 128, 0, Wb, wv, lane);  // drains at next barA, under mlp2
    // ---- mlp2 partial: oacc += H x W2c -> D[tok@lr*4+r][col@lc] ----
    #pragma unroll
    for (int kt=0; kt<2; kt++){
      s16x8 hf[4], wf[4];
      #pragma unroll
      for (int mi=0;mi<4;mi++)
        hf[mi] = *(const s16x8*)&Hb[(wr*64+mi*16+lc)*64 + (((kt*4+lr) ^ ((wr*64+mi*16+lc)&7))*8)];
      #pragma unroll
      for (int nj=0;nj<4;nj++)
        wf[nj] = *(const s16x8*)&W2T[(size_t)(wc*64+nj*16+lc)*512 + ck*64 + kt*32 + lr*8];
      #pragma unroll
      for (int mi=0;mi<4;mi++)
        #pragma unroll
        for (int nj=0;nj<4;nj++)
          oacc[mi][nj] = __builtin_amdgcn_mfma_f32_16x16x32_bf16(hf[mi], wf[nj], oacc[mi][nj], 0,0,0);
    }
  }

  // ---- adapter1: a2 = A1 x Xn -> D[hid@lr*4+r][tok@lc], hid<32 (both wc redundant) ----
  f32x4 a2[4][2];
  #pragma unroll
  for (int mi=0;mi<4;mi++){ a2[mi][0]=(f32x4){0.f,0.f,0.f,0.f}; a2[mi][1]=(f32x4){0.f,0.f,0.f,0.f}; }
  #pragma unroll
  for (int kt=0; kt<4; kt++){
    s16x8 af[4];
    #pragma unroll
    for (int mi=0;mi<4;mi++)
      af[mi] = *(const s16x8*)&As[(wr*64+mi*16+lc)*128 + (((kt*4+lr) ^ (lc&7))*8)];
    s16x8 bA = *(const s16x8*)&A1T[(size_t)lc*128 + kt*32 + lr*8];
    s16x8 bB = *(const s16x8*)&A1T[(size_t)(16+lc)*128 + kt*32 + lr*8];
    #pragma unroll
    for (int mi=0;mi<4;mi++){
      a2[mi][0] = __builtin_amdgcn_mfma_f32_16x16x32_bf16(bA, af[mi], a2[mi][0], 0,0,0);
      a2[mi][1] = __builtin_amdgcn_mfma_f32_16x16x32_bf16(bB, af[mi], a2[mi][1], 0,0,0);
    }
  }
  __syncthreads();   // all Xn reads of As done; last chunk's Hb reads done
  // ---- Hq (x0.5 folded) -> As[tok*64 + swz(hid)] (16B-aligned slots) ----
  if (wc==0){
    #pragma unroll
    for (int nj=0;nj<2;nj++){
      const int hb = nj*16 + lr*4;
      float4 b4 = *(const float4*)&ab1[hb];
      #pragma unroll
      for (int mi=0;mi<4;mi++){
        const int tok = wr*64 + mi*16 + lc;
        uint2 pk;
        pk.x = cvtpk(0.5f*gelu_f(a2[mi][nj][0]+b4.x), 0.5f*gelu_f(a2[mi][nj][1]+b4.y));
        pk.y = cvtpk(0.5f*gelu_f(a2[mi][nj][2]+b4.z), 0.5f*gelu_f(a2[mi][nj][3]+b4.w));
        *(uint2*)&As[tok*64 + (((hb>>3) ^ (tok&7))*8) + (hb&7)] = pk;
      }
    }
  }
  __syncthreads();
  // ---- adapter2: oacc += Hq x A2 (K=32, one mfma per tile) ----
  {
    s16x8 hqf[4];
    #pragma unroll
    for (int mi=0;mi<4;mi++){
      const int tok = wr*64 + mi*16 + lc;
      hqf[mi] = *(const s16x8*)&As[tok*64 + ((lr ^ (tok&7))*8)];
    }
    #pragma unroll
    for (int nj=0;nj<4;nj++){
      s16x8 a2f = *(const s16x8*)&A2T[(size_t)(wc*64+nj*16+lc)*32 + lr*8];
      #pragma unroll
      for (int mi=0;mi<4;mi++)
        oacc[mi][nj] = __builtin_amdgcn_mfma_f32_16x16x32_bf16(hqf[mi], a2f, oacc[mi][nj], 0,0,0);
    }
  }
  // ---- epilogue: out += oacc + b2 + 0.5*ab2 (64B-coalesced scalar f32 RMW) ----
  #pragma unroll
  for (int nj=0;nj<4;nj++){
    const int col = wc*64 + nj*16 + lc;
    const float badd = b2[col] + 0.5f*ab2[col];
    #pragma unroll
    for (int mi=0;mi<4;mi++){
      #pragma unroll
      for (int r=0;r<4;r++){
        const size_t row = row0 + wr*64 + mi*16 + lr*4 + r;
        outp[row*128 + col] += oacc[mi][nj][r] + badd;
      }
    }
  }
}

// ---------------- temporal attention (T=8 per (b,l), 4 heads), bf16 out ----------------
__global__ __launch_bounds__(256) void t_attn_kernel(const u16* __restrict__ qkv,
    const float* __restrict__ tpb, u16* __restrict__ o)
{
  const int tid = threadIdx.x;
  const int li = tid>>5, h = (tid>>3)&3, t = tid&7;
  const int b = blockIdx.x/392, lt = blockIdx.x%392;
  const int l = lt*8+li;
  const size_t rowt = (size_t)(b*8+t)*LDIM + l;
  const u16* qp = qkv + rowt*384 + h*32;
  f32x8 q0 = ldbf8(qp)   *SCALE_F, q1 = ldbf8(qp+8) *SCALE_F,
        q2 = ldbf8(qp+16)*SCALE_F, q3 = ldbf8(qp+24)*SCALE_F;
  float s[8];
  #pragma unroll
  for (int t2=0;t2<8;t2++){
    const u16* kp = qkv + ((size_t)(b*8+t2)*LDIM + l)*384 + 128 + h*32;
    f32x8 d = q0*ldbf8(kp) + q1*ldbf8(kp+8) + q2*ldbf8(kp+16) + q3*ldbf8(kp+24);
    s[t2] = sum8(d) + tpb[(t-t2+7)*4 + h];
  }
  float m = s[0];
  #pragma unroll
  for (int t2=1;t2<8;t2++) m = fmaxf(m, s[t2]);
  float ssum = 0.f;
  #pragma unroll
  for (int t2=0;t2<8;t2++){ s[t2] = __expf(s[t2]-m); ssum += s[t2]; }
  const float inv = 1.0f/ssum;
  f32x8 o0={0,0,0,0,0,0,0,0}, o1={0,0,0,0,0,0,0,0},
        o2={0,0,0,0,0,0,0,0}, o3={0,0,0,0,0,0,0,0};
  #pragma unroll
  for (int t2=0;t2<8;t2++){
    const u16* vp = qkv + ((size_t)(b*8+t2)*LDIM + l)*384 + 256 + h*32;
    float aw = s[t2]*inv;
    o0 += aw*ldbf8(vp); o1 += aw*ldbf8(vp+8); o2 += aw*ldbf8(vp+16); o3 += aw*ldbf8(vp+24);
  }
  u16* op = o + rowt*128 + h*32;
  *(u16x8*)op      = pack8(o0); *(u16x8*)(op+8)  = pack8(o1);
  *(u16x8*)(op+16) = pack8(o2); *(u16x8*)(op+24) = pack8(o3);
}

// --------- MFMA shifted-window spatial attention ---------
__global__ __launch_bounds__(256,2) void s_attn_mfma(const u16* __restrict__ qkv,
    const float* __restrict__ rpb, u16* __restrict__ o)
{
  __shared__ u16 Qs[64][136];
  __shared__ u16 Ks[64][136];
  __shared__ u16 Vt[128][72];
  __shared__ float rpbL[676];
  __shared__ int rowL[49];
  __shared__ int codeL[49];
  const int tid = threadIdx.x;
  const int bidx = blockIdx.x;
  const int bt = bidx>>6, wh = (bidx>>3)&7, ww = bidx&7;
  if (tid < 49){
    int ph = tid/7, pwv = tid%7;
    int rh = wh*7+ph, rw = ww*7+pwv;
    int oh = rh+3; if (oh>=56) oh-=56;   // roll(-3)
    int ow = rw+3; if (ow>=56) ow-=56;
    rowL[tid] = bt*LDIM + oh*56 + ow;
    codeL[tid] = ((rh<49)?0:((rh<53)?1:2))*3 + ((rw<49)?0:((rw<53)?1:2));
  }
  for (int i2 = tid; i2 < 676; i2 += 256) rpbL[i2] = rpb[i2];
  for (int idx = tid; idx < 128*15; idx += 256){
    int d = idx/15, jj = 49 + (idx - d*15);
    Vt[d][jj] = 0;
  }
  __syncthreads();
  #pragma unroll
  for (int it = 0; it < 10; it++){
    int idx = it*256 + tid;
    if (idx < 2352){
      int j = idx/48, s = idx - j*48;
      const u16* src = qkv + (size_t)rowL[j]*384 + s*8;
      u16x8 v = *(const u16x8*)src;
      if (s < 16)      *(u16x8*)&Qs[j][s*8] = v;
      else if (s < 32) *(u16x8*)&Ks[j][(s-16)*8] = v;
      else { int c0 = (s-32)*8;
        #pragma unroll
        for (int e=0;e<8;e++) Vt[c0+e][j] = v[e];
      }
    }
  }
  __syncthreads();

  const int h = tid>>6, lane = tid&63, lr = lane>>4, lc = lane&15;
  s16x8 qf[4], kf[4];
  #pragma unroll
  for (int t=0;t<4;t++){
    qf[t] = *(const s16x8*)&Qs[t*16+lc][h*32+lr*8];
    kf[t] = *(const s16x8*)&Ks[t*16+lc][h*32+lr*8];
  }
  f32x4 sa[4][4];
  #pragma unroll
  for (int tj=0;tj<4;tj++){
    #pragma unroll
    for (int ti=0;ti<4;ti++)
      sa[tj][ti] = __builtin_amdgcn_mfma_f32_16x16x32_bf16(kf[tj], qf[ti], (f32x4){0.f,0.f,0.f,0.f}, 0,0,0);
  }
  int ihv[4], iwv[4], civ[4];
  #pragma unroll
  for (int ti=0;ti<4;ti++){
    int i = ti*16+lc; int im = (i<49)? i:48;
    int ih2 = (im*147)>>10; ihv[ti]=ih2; iwv[ti]=im-ih2*7; civ[ti]=codeL[im];
  }
  float rs[4] = {0.f,0.f,0.f,0.f};
  #pragma unroll
  for (int tj=0;tj<4;tj++){
    #pragma unroll
    for (int r=0;r<4;r++){
      int j = tj*16 + lr*4 + r;
      bool jv = (j<49);
      int jm = jv? j:48;
      int jh2 = (jm*147)>>10; int jw2 = jm - jh2*7; int cj = codeL[jm];
      #pragma unroll
      for (int ti=0;ti<4;ti++){
        float sv = sa[tj][ti][r]*SCALE_F
                 + rpbL[((ihv[ti]-jh2+6)*13 + (iwv[ti]-jw2+6))*4 + h];
        if (civ[ti] != cj) sv -= 100.f;
        float pv = jv ? __expf(sv) : 0.f;
        sa[tj][ti][r] = pv;
        rs[ti] += pv;
      }
    }
  }
  #pragma unroll
  for (int ti=0;ti<4;ti++){
    float t2 = rs[ti];
    t2 += __shfl_xor(t2, 16);
    t2 += __shfl_xor(t2, 32);
    rs[ti] = 1.0f/t2;
  }
  unsigned lo[4][4], hi[4][4];
  #pragma unroll
  for (int tj=0;tj<4;tj++){
    #pragma unroll
    for (int ti=0;ti<4;ti++){
      float inv = rs[ti];
      lo[tj][ti] = cvtpk(sa[tj][ti][0]*inv, sa[tj][ti][1]*inv);
      hi[tj][ti] = cvtpk(sa[tj][ti][2]*inv, sa[tj][ti][3]*inv);
    }
  }
  f32x4 oa[4][2];
  #pragma unroll
  for (int mi=0;mi<4;mi++){ oa[mi][0]=(f32x4){0.f,0.f,0.f,0.f}; oa[mi][1]=(f32x4){0.f,0.f,0.f,0.f}; }
  const int srcA = lc + ((lane>>4)&1)*32;
  const int srcB = srcA + 16;
  const bool hiHalf = (lr>=2);
  #pragma unroll
  for (int kt=0;kt<2;kt++){
    s16x8 vf[2];
    #pragma unroll
    for (int nd=0;nd<2;nd++)
      vf[nd] = *(const s16x8*)&Vt[h*32 + nd*16 + lc][kt*32 + lr*8];
    #pragma unroll
    for (int mi=0;mi<4;mi++){
      unsigned wA0 = __shfl(lo[2*kt][mi],   srcA), wB0 = __shfl(lo[2*kt+1][mi], srcA);
      unsigned wA1 = __shfl(hi[2*kt][mi],   srcA), wB1 = __shfl(hi[2*kt+1][mi], srcA);
      unsigned wA2 = __shfl(lo[2*kt][mi],   srcB), wB2 = __shfl(lo[2*kt+1][mi], srcB);
      unsigned wA3 = __shfl(hi[2*kt][mi],   srcB), wB3 = __shfl(hi[2*kt+1][mi], srcB);
      union { unsigned u[4]; s16x8 v8; } cv;
      cv.u[0] = hiHalf? wB0 : wA0;
      cv.u[1] = hiHalf? wB1 : wA1;
      cv.u[2] = hiHalf? wB2 : wA2;
      cv.u[3] = hiHalf? wB3 : wA3;
      #pragma unroll
      for (int nd=0;nd<2;nd++)
        oa[mi][nd] = __builtin_amdgcn_mfma_f32_16x16x32_bf16(cv.v8, vf[nd], oa[mi][nd], 0,0,0);
    }
  }
  #pragma unroll
  for (int mi=0;mi<4;mi++){
    #pragma unroll
    for (int r=0;r<4;r++){
      int i = mi*16 + lr*4 + r;
      if (i < 49){
        size_t orow = (size_t)rowL[i]*128 + h*32;
        o[orow + lc]      = f2bf(oa[mi][0][r]);
        o[orow + 16 + lc] = f2bf(oa[mi][1][r]);
      }
    }
  }
}

extern "C" void kernel_launch(void* const* d_in, const int* in_sizes, int n_in,
                              void* d_out, int out_size, void* d_ws, size_t ws_size,
                              hipStream_t stream)
{
  (void)in_sizes; (void)n_in; (void)out_size; (void)ws_size;
  const float* x      = (const float*)d_in[0];
  const float* qkv_w  = (const float*)d_in[1];
  const float* qkv_b  = (const float*)d_in[2];
  const float* proj_w = (const float*)d_in[3];
  const float* proj_b = (const float*)d_in[4];
  const float* rpb    = (const float*)d_in[5];
  const float* tpb    = (const float*)d_in[6];
  const float* n1g    = (const float*)d_in[7];
  const float* n1b    = (const float*)d_in[8];
  const float* n2g    = (const float*)d_in[9];
  const float* n2b    = (const float*)d_in[10];
  const float* mw1    = (const float*)d_in[11];
  const float* mb1    = (const float*)d_in[12];
  const float* mw2    = (const float*)d_in[13];
  const float* mb2    = (const float*)d_in[14];
  const float* sw1    = (const float*)d_in[15];
  const float* sb1    = (const float*)d_in[16];
  const float* sw2    = (const float*)d_in[17];
  const float* sb2    = (const float*)d_in[18];
  const float* tw1    = (const float*)d_in[19];
  const float* tb1    = (const float*)d_in[20];
  const float* tw2    = (const float*)d_in[21];
  const float* tb2    = (const float*)d_in[22];
  const float* aw1    = (const float*)d_in[23];
  const float* ab1    = (const float*)d_in[24];
  const float* aw2    = (const float*)d_in[25];
  const float* ab2    = (const float*)d_in[26];

  char* ws = (char*)d_ws;
  u16*   Xn  = (u16*)(ws);
  u16*   QKV = (u16*)(ws + 25690112ULL);
  u16*   O   = (u16*)(ws + 102760448ULL);
  float* Cb  = (float*)(ws + 134873088ULL);
  u16*   WT  = (u16*)(ws + 186253312ULL);
  float* out = (float*)d_out;

  const u16 *WTqkv=WT, *WTproj=WT+49152, *WTm1=WT+65536, *WTm2=WT+131072,
            *WTt1=WT+196608, *WTt2=WT+200704, *WTs1=WT+204800, *WTs2=WT+208896,
            *WTa1=WT+212992, *WTa2=WT+217088;

  WSrc srcs; srcs.p[0]=qkv_w; srcs.p[1]=proj_w; srcs.p[2]=mw1; srcs.p[3]=mw2;
  srcs.p[4]=tw1; srcs.p[5]=tw2; srcs.p[6]=sw1; srcs.p[7]=sw2; srcs.p[8]=aw1; srcs.p[9]=aw2;
  prep_w<<<864,256,0,stream>>>(srcs, WT);

  // ---- temporal attention + T_Adapter (+fused LN of its output) ----
  ln_kernel<<<25088,256,0,stream>>>(x, n1g, n1b, Xn);
  gemm_tile<1,3,0><<<784,256,0,stream>>>(Xn, WTqkv, qkv_b, QKV, 384, nullptr,nullptr);
  t_attn_kernel<<<1568,256,0,stream>>>(QKV, tpb, O);
  proj_ada_tile<0><<<784,256,0,stream>>>(O, WTproj, proj_b, WTt1, tb1, WTt2, tb2,
                                          x, Cb, n1g, n1b, Xn);
  // ---- shifted-window spatial attention + S_Adapter (+fused LN2) ----
  gemm_tile<1,3,0><<<784,256,0,stream>>>(Xn, WTqkv, qkv_b, QKV, 384, nullptr,nullptr);
  s_attn_mfma<<<2048,256,0,stream>>>(QKV, rpb, O);
  proj_ada_tile<1><<<784,256,0,stream>>>(O, WTproj, proj_b, WTs1, sb1, WTs2, sb2,
                                          Cb, out, n2g, n2b, Xn);
  // ---- fully fused MLP + MLP_Adapter (v4) ----
  mlp_fused<<<784,256,0,stream>>>(Xn, WTm1, mb1, WTm2, mb2, WTa1, ab1, WTa2, ab2, out);
}

// Round 18
// 366.353 us; speedup vs baseline: 1.0288x; 1.0258x over previous
//
#include <hip/hip_runtime.h>

#define TOKS 100352   // BT*L = 32*3136
#define LDIM 3136     // H*W
#define SCALE_F 0.17677669529663687f  // 32^-0.5

typedef unsigned short u16;
typedef u16   u16x8 __attribute__((ext_vector_type(8)));
typedef short s16x8 __attribute__((ext_vector_type(8)));
typedef float f32x8 __attribute__((ext_vector_type(8)));
typedef float f32x4 __attribute__((ext_vector_type(4)));

__device__ __forceinline__ float bf2f(u16 u){ return __uint_as_float(((unsigned)u)<<16); }
__device__ __forceinline__ u16 f2bf(float f){
  unsigned u = __float_as_uint(f);
  return (u16)((u + 0x7FFFu + ((u>>16)&1u)) >> 16);   // RNE
}
// packed bf16 convert: lo=cvt(a), hi=cvt(b)  (RNE) — single VALU instr
__device__ __forceinline__ unsigned cvtpk(float a, float b){
  unsigned r;
  asm("v_cvt_pk_bf16_f32 %0, %1, %2" : "=v"(r) : "v"(a), "v"(b));
  return r;
}
__device__ __forceinline__ f32x8 ldbf8(const u16* p){
  u16x8 u = *(const u16x8*)p;
  f32x8 f;
  #pragma unroll
  for (int j=0;j<8;j++) f[j] = bf2f(u[j]);
  return f;
}
__device__ __forceinline__ u16x8 pack8(f32x8 v){
  u16x8 r;
  #pragma unroll
  for (int j=0;j<8;j++) r[j] = f2bf(v[j]);
  return r;
}
__device__ __forceinline__ float sum8(f32x8 a){
  return ((a[0]+a[1])+(a[2]+a[3]))+((a[4]+a[5])+(a[6]+a[7]));
}
// sigmoid-form gelu with raw HW rcp (1 instr vs full IEEE div sequence).
// NaN-free: x->-inf => exp->inf => rcp->0 => -0; x->+inf => x*rcp(1)=x.
__device__ __forceinline__ float gelu_f(float x){
  return x * __builtin_amdgcn_rcpf(1.0f + __expf(-1.702f*x));
}

// ---- async global->LDS, 16B per lane; LDS dest = wave-uniform base + lane*16 ----
__device__ __forceinline__ void gl16(const u16* g, u16* l){
  __builtin_amdgcn_global_load_lds(
      (const __attribute__((address_space(1))) unsigned*)(const void*)g,
      (__attribute__((address_space(3))) unsigned*)(void*)l, 16, 0, 0);
}
// stage ROWS x 128 bf16 tile into XOR-swizzled LDS (slot = kb ^ (r&7)) via
// pre-swizzled per-lane SOURCE (rule: linear dest + inverse-swz source + swz read).
template<int ITERS>
__device__ __forceinline__ void stage_tileN(const u16* __restrict__ src, size_t rowstart,
    int KTOT, int koff, u16* lds, int wv, int lane){
  const int rr = wv*4 + (lane>>4);
  const int sl = lane&15;
  const int kb = sl ^ (rr&7);
  const u16* g0 = src + (rowstart + rr)*(size_t)KTOT + koff + kb*8;
  u16* l0 = lds + wv*4*128;
  #pragma unroll
  for (int it=0; it<ITERS; it++)
    gl16(g0 + (size_t)it*16*KTOT, l0 + it*16*128);
}
__device__ __forceinline__ void stage_tile(const u16* __restrict__ src, size_t rowstart,
    int KTOT, int koff, u16* lds, int wv, int lane){
  stage_tileN<8>(src, rowstart, KTOT, koff, lds, wv, lane);
}

// ---------------- weight prep: f32 (K,N) -> bf16 transposed (N,K) ----------------
struct WSrc { const float* p[10]; };
__global__ __launch_bounds__(256) void prep_w(WSrc s, u16* __restrict__ dst){
  const int Ks[10]={128,128,128,512,128,32,128,32,128,32};
  const int Ns[10]={384,128,512,128,32,128,32,128,32,128};
  const int off[11]={0,49152,65536,131072,196608,200704,204800,208896,212992,217088,221184};
  int idx = blockIdx.x*256+threadIdx.x;
  int m=0;
  #pragma unroll
  for (int i=0;i<10;i++) if (idx>=off[i+1]) m=i+1;
  int e = idx-off[m];
  int K=Ks[m], Nn=Ns[m];
  int n=e/K, k=e-n*K;
  dst[idx] = f2bf(s.p[m][k*Nn+n]);
}

// ---------------- LayerNorm: one wave per token (C=128), bf16 out ----------------
__global__ __launch_bounds__(256) void ln_kernel(const float* __restrict__ x,
    const float* __restrict__ g, const float* __restrict__ bta, u16* __restrict__ out)
{
  int tok  = (int)((blockIdx.x*256u + threadIdx.x) >> 6);
  int lane = threadIdx.x & 63;
  const float* xr = x + (size_t)tok*128;
  float v0 = xr[lane], v1 = xr[lane+64];
  float s = v0+v1;
  #pragma unroll
  for (int o=32;o;o>>=1) s += __shfl_xor(s,o);
  float m = s*(1.0f/128.0f);
  float d0=v0-m, d1=v1-m;
  float q = d0*d0+d1*d1;
  #pragma unroll
  for (int o=32;o;o>>=1) q += __shfl_xor(q,o);
  float rs = rsqrtf(q*(1.0f/128.0f)+1e-5f);
  u16* orow = out + (size_t)tok*128;
  orow[lane]    = f2bf(d0*rs*g[lane]   + bta[lane]);
  orow[lane+64] = f2bf(d1*rs*g[lane+64]+ bta[lane+64]);
}

// ======== Tiled MFMA GEMM, SWAPPED operands: D[col @ lr*4+r][row @ lc] ========
// EPI: 0 = bf16 bias (direct uint2 stores); 1 = + gelu
template<int KCH, int NTC, int EPI>
__global__ __launch_bounds__(256,2) void gemm_tile(
    const u16* __restrict__ X, const u16* __restrict__ WT,
    const float* __restrict__ bias, void* outp, int N,
    const float* res1, const u16* __restrict__ adab)
{
  constexpr int KTOT = KCH*128;
  __shared__ u16 As[128*128];
  __shared__ u16 Bs[128*128];
  const int tid = threadIdx.x;
  const int wv = tid>>6, lane = tid&63, lr = lane>>4, lc = lane&15;
  const int wr = wv>>1, wc = wv&1;
  const size_t row0 = (size_t)blockIdx.x*128;

  f32x4 acc[4][4];
  #pragma unroll
  for (int mi=0;mi<4;mi++)
    #pragma unroll
    for (int nj=0;nj<4;nj++) acc[mi][nj] = (f32x4){0.f,0.f,0.f,0.f};

  for (int kc=0; kc<KCH; kc++){
    for (int nt=0; nt<NTC; nt++){
      if (kc+nt > 0) __syncthreads();
      if (nt == 0) stage_tile(X, row0, KTOT, kc*128, As, wv, lane);
      stage_tile(WT, (size_t)nt*128, KTOT, kc*128, Bs, wv, lane);
      __syncthreads();
      #pragma unroll
      for (int kt=0; kt<4; kt++){
        s16x8 af[4], bfr[4];
        #pragma unroll
        for (int mi=0;mi<4;mi++){
          int row = wr*64 + mi*16 + lc;
          af[mi] = *(const s16x8*)&As[row*128 + (((kt*4+lr) ^ (lc&7))*8)];
        }
        #pragma unroll
        for (int nj=0;nj<4;nj++){
          int col = wc*64 + nj*16 + lc;
          bfr[nj] = *(const s16x8*)&Bs[col*128 + (((kt*4+lr) ^ (lc&7))*8)];
        }
        #pragma unroll
        for (int mi=0;mi<4;mi++)
          #pragma unroll
          for (int nj=0;nj<4;nj++)
            acc[mi][nj] = __builtin_amdgcn_mfma_f32_16x16x32_bf16(bfr[nj], af[mi], acc[mi][nj], 0,0,0);
      }
      {
        #pragma unroll
        for (int nj=0;nj<4;nj++){
          const int colb = nt*128 + wc*64 + nj*16 + lr*4;
          float4 b4 = *(const float4*)&bias[colb];
          #pragma unroll
          for (int mi=0;mi<4;mi++){
            const size_t row = row0 + wr*64 + mi*16 + lc;
            float v0=acc[mi][nj][0]+b4.x, v1=acc[mi][nj][1]+b4.y,
                  v2=acc[mi][nj][2]+b4.z, v3=acc[mi][nj][3]+b4.w;
            if constexpr (EPI==1){ v0=gelu_f(v0); v1=gelu_f(v1); v2=gelu_f(v2); v3=gelu_f(v3); }
            uint2 pk; pk.x = cvtpk(v0,v1); pk.y = cvtpk(v2,v3);
            *(uint2*)&((u16*)outp)[row*(size_t)N + colb] = pk;
            acc[mi][nj] = (f32x4){0.f,0.f,0.f,0.f};
          }
        }
      }
    }
  }
  (void)res1; (void)adab;
}

// ======== Fused proj + adapter + residual + LayerNorm (row-local) ========
template<int SMODE>
__global__ __launch_bounds__(256,2) void proj_ada_tile(
    const u16* __restrict__ O, const u16* __restrict__ PW, const float* __restrict__ pb,
    const u16* __restrict__ W1T, const float* __restrict__ b1,
    const u16* __restrict__ W2T, const float* __restrict__ b2,
    const float* __restrict__ res1, float* __restrict__ outp,
    const float* __restrict__ gn, const float* __restrict__ gb, u16* __restrict__ xnout)
{
  __shared__ u16 As[128*128];
  __shared__ u16 Bs[128*128];
  __shared__ u16 Hs[4][32][40];
  const int tid = threadIdx.x;
  const int wv = tid>>6, lane = tid&63, lr = lane>>4, lc = lane&15;
  const int wr = wv>>1, wc = wv&1;
  const size_t row0 = (size_t)blockIdx.x*128;
  stage_tile(O, row0, 128, 0, As, wv, lane);
  stage_tile(PW, 0, 128, 0, Bs, wv, lane);
  __syncthreads();
  f32x4 acc[4][4];
  #pragma unroll
  for (int mi=0;mi<4;mi++)
    #pragma unroll
    for (int nj=0;nj<4;nj++) acc[mi][nj] = (f32x4){0.f,0.f,0.f,0.f};
  #pragma unroll
  for (int kt=0; kt<4; kt++){
    s16x8 af[4], bfr[4];
    #pragma unroll
    for (int mi=0;mi<4;mi++)
      af[mi] = *(const s16x8*)&As[(wr*64+mi*16+lc)*128 + (((kt*4+lr) ^ (lc&7))*8)];
    #pragma unroll
    for (int nj=0;nj<4;nj++)
      bfr[nj] = *(const s16x8*)&Bs[(wc*64+nj*16+lc)*128 + (((kt*4+lr) ^ (lc&7))*8)];
    #pragma unroll
    for (int mi=0;mi<4;mi++)
      #pragma unroll
      for (int nj=0;nj<4;nj++)
        acc[mi][nj] = __builtin_amdgcn_mfma_f32_16x16x32_bf16(bfr[nj], af[mi], acc[mi][nj], 0,0,0);
  }
  __syncthreads();
  #pragma unroll
  for (int nj=0;nj<4;nj++){
    const int colb = wc*64 + nj*16 + lr*4;
    float4 b4 = *(const float4*)&pb[colb];
    #pragma unroll
    for (int mi=0;mi<4;mi++){
      const int row = wr*64 + mi*16 + lc;
      uint2 pk;
      pk.x = cvtpk(acc[mi][nj][0]+b4.x, acc[mi][nj][1]+b4.y);
      pk.y = cvtpk(acc[mi][nj][2]+b4.z, acc[mi][nj][3]+b4.w);
      *(uint2*)&As[row*128 + (((colb>>3) ^ (row&7))*8) + (colb&7)] = pk;
    }
  }
  __syncthreads();
  const int rbase = wv*32;
  f32x4 a2[2][2];
  #pragma unroll
  for (int mi=0;mi<2;mi++){ a2[mi][0]=(f32x4){0.f,0.f,0.f,0.f}; a2[mi][1]=(f32x4){0.f,0.f,0.f,0.f}; }
  #pragma unroll
  for (int kt=0; kt<4; kt++){
    s16x8 af0 = *(const s16x8*)&As[(rbase+lc)*128 + (((kt*4+lr) ^ (lc&7))*8)];
    s16x8 af1 = *(const s16x8*)&As[(rbase+16+lc)*128 + (((kt*4+lr) ^ (lc&7))*8)];
    #pragma unroll
    for (int nj=0; nj<2; nj++){
      s16x8 b = *(const s16x8*)&W1T[(size_t)(nj*16+lc)*128 + kt*32 + lr*8];
      a2[0][nj] = __builtin_amdgcn_mfma_f32_16x16x32_bf16(b, af0, a2[0][nj], 0,0,0);
      a2[1][nj] = __builtin_amdgcn_mfma_f32_16x16x32_bf16(b, af1, a2[1][nj], 0,0,0);
    }
  }
  #pragma unroll
  for (int nj=0;nj<2;nj++){
    const int hb = nj*16 + lr*4;
    float4 b4 = *(const float4*)&b1[hb];
    #pragma unroll
    for (int mi=0;mi<2;mi++){
      const int tok = mi*16 + lc;
      uint2 pk;
      pk.x = cvtpk(gelu_f(a2[mi][nj][0]+b4.x), gelu_f(a2[mi][nj][1]+b4.y));
      pk.y = cvtpk(gelu_f(a2[mi][nj][2]+b4.z), gelu_f(a2[mi][nj][3]+b4.w));
      *(uint2*)&Hs[wv][tok][hb] = pk;
    }
  }
  f32x4 a3[2][8];
  #pragma unroll
  for (int mi=0;mi<2;mi++){
    s16x8 af = *(const s16x8*)&Hs[wv][mi*16+lc][lr*8];
    #pragma unroll
    for (int nj=0;nj<8;nj++){
      s16x8 b = *(const s16x8*)&W2T[(size_t)(nj*16+lc)*32 + lr*8];
      a3[mi][nj] = __builtin_amdgcn_mfma_f32_16x16x32_bf16(b, af, (f32x4){0.f,0.f,0.f,0.f}, 0,0,0);
    }
  }
  float sum[2]={0.f,0.f}, sq[2]={0.f,0.f};
  #pragma unroll
  for (int mi=0;mi<2;mi++){
    const int rl = rbase + mi*16 + lc;
    const size_t row = row0 + rl;
    #pragma unroll
    for (int nj=0;nj<8;nj++){
      const int colb = nj*16 + lr*4;
      float4 b4 = *(const float4*)&b2[colb];
      float4 r4 = *(const float4*)&res1[row*128 + colb];
      f32x4 v;
      v[0]=a3[mi][nj][0]+b4.x+r4.x; v[1]=a3[mi][nj][1]+b4.y+r4.y;
      v[2]=a3[mi][nj][2]+b4.z+r4.z; v[3]=a3[mi][nj][3]+b4.w+r4.w;
      if constexpr (SMODE==1){
        uint2 pu = *(const uint2*)&As[rl*128 + (((colb>>3) ^ (rl&7))*8) + (colb&7)];
        v[0] += bf2f((u16)(pu.x&0xffff)); v[1] += bf2f((u16)(pu.x>>16));
        v[2] += bf2f((u16)(pu.y&0xffff)); v[3] += bf2f((u16)(pu.y>>16));
      }
      float4 st; st.x=v[0]; st.y=v[1]; st.z=v[2]; st.w=v[3];
      *(float4*)&outp[row*128 + colb] = st;
      a3[mi][nj] = v;
      sum[mi] += (v[0]+v[1])+(v[2]+v[3]);
      sq[mi]  += (v[0]*v[0]+v[1]*v[1])+(v[2]*v[2]+v[3]*v[3]);
    }
  }
  #pragma unroll
  for (int mi=0;mi<2;mi++){
    float s2 = sum[mi], q2 = sq[mi];
    s2 += __shfl_xor(s2,16); s2 += __shfl_xor(s2,32);
    q2 += __shfl_xor(q2,16); q2 += __shfl_xor(q2,32);
    float mean = s2*(1.0f/128.0f);
    float var  = q2*(1.0f/128.0f) - mean*mean;
    float rs   = rsqrtf(var + 1e-5f);
    const size_t row = row0 + rbase + mi*16 + lc;
    #pragma unroll
    for (int nj=0;nj<8;nj++){
      const int colb = nj*16 + lr*4;
      float4 g4 = *(const float4*)&gn[colb];
      float4 h4 = *(const float4*)&gb[colb];
      uint2 pk;
      pk.x = cvtpk((a3[mi][nj][0]-mean)*rs*g4.x + h4.x,
                   (a3[mi][nj][1]-mean)*rs*g4.y + h4.y);
      pk.y = cvtpk((a3[mi][nj][2]-mean)*rs*g4.z + h4.z,
                   (a3[mi][nj][3]-mean)*rs*g4.w + h4.w);
      *(uint2*)&xnout[row*128 + colb] = pk;
    }
  }
}

// ======== Fused MLP v4: separate 16KB W1-chunk + 16KB H buffers, 64-hid chunks.
__global__ __launch_bounds__(256,2) void mlp_fused(
    const u16* __restrict__ X, const u16* __restrict__ W1T, const float* __restrict__ b1,
    const u16* __restrict__ W2T, const float* __restrict__ b2,
    const u16* __restrict__ A1T, const float* __restrict__ ab1,
    const u16* __restrict__ A2T, const float* __restrict__ ab2,
    float* __restrict__ outp)
{
  __shared__ u16 As[128*128];   // X, swizzled (staged once)
  __shared__ u16 Wb[64*128];    // W1 chunk (64 hid rows x 128 K), swizzled
  __shared__ u16 Hb[128*64];    // H (128 tok x 64 hid), slot-swizzled
  const int tid = threadIdx.x;
  const int wv = tid>>6, lane = tid&63, lr = lane>>4, lc = lane&15;
  const int wr = wv>>1, wc = wv&1;
  const size_t row0 = (size_t)blockIdx.x*128;

  stage_tile(X, row0, 128, 0, As, wv, lane);
  stage_tileN<4>(W1T, 0, 128, 0, Wb, wv, lane);
  __syncthreads();

  f32x4 oacc[4][4];
  #pragma unroll
  for (int mi=0;mi<4;mi++)
    #pragma unroll
    for (int nj=0;nj<4;nj++) oacc[mi][nj] = (f32x4){0.f,0.f,0.f,0.f};

  for (int ck=0; ck<8; ck++){
    if (ck > 0) __syncthreads();   // barA: drains W1[ck] stage; prev Hb reads done
    // ---- mlp1: acc = W1c x Xn -> D[hid@lr*4+r][tok@lc], 64 hid ----
    f32x4 acc[4][2];
    #pragma unroll
    for (int mi=0;mi<4;mi++)
      #pragma unroll
      for (int nj=0;nj<2;nj++) acc[mi][nj] = (f32x4){0.f,0.f,0.f,0.f};
    #pragma unroll
    for (int kt=0; kt<4; kt++){
      s16x8 af[4], bfr[2];
      #pragma unroll
      for (int mi=0;mi<4;mi++)
        af[mi] = *(const s16x8*)&As[(wr*64+mi*16+lc)*128 + (((kt*4+lr) ^ (lc&7))*8)];
      #pragma unroll
      for (int nj=0;nj<2;nj++)
        bfr[nj] = *(const s16x8*)&Wb[(wc*32+nj*16+lc)*128 + (((kt*4+lr) ^ (lc&7))*8)];
      #pragma unroll
      for (int mi=0;mi<4;mi++)
        #pragma unroll
        for (int nj=0;nj<2;nj++)
          acc[mi][nj] = __builtin_amdgcn_mfma_f32_16x16x32_bf16(bfr[nj], af[mi], acc[mi][nj], 0,0,0);
    }
    // ---- H = gelu(acc+b1) -> Hb[tok][hid] ----
    #pragma unroll
    for (int nj=0;nj<2;nj++){
      const int hidb = wc*32 + nj*16 + lr*4;
      float4 b4 = *(const float4*)&b1[ck*64 + hidb];
      #pragma unroll
      for (int mi=0;mi<4;mi++){
        const int tok = wr*64 + mi*16 + lc;
        uint2 pk;
        pk.x = cvtpk(gelu_f(acc[mi][nj][0]+b4.x), gelu_f(acc[mi][nj][1]+b4.y));
        pk.y = cvtpk(gelu_f(acc[mi][nj][2]+b4.z), gelu_f(acc[mi][nj][3]+b4.w));
        *(uint2*)&Hb[tok*64 + (((hidb>>3) ^ (tok&7))*8) + (hidb&7)] = pk;
      }
    }
    __syncthreads();   // barC: H visible; all mlp1 Wb reads done
    if (ck < 7) stage_tileN<4>(W1T, (size_t)(ck+1)*64, 128, 0, Wb, wv, lane);  // drains at next barA
    // ---- mlp2 partial: oacc += H x W2c -> D[tok@lr*4+r][col@lc] ----
    #pragma unroll
    for (int kt=0; kt<2; kt++){
      s16x8 hf[4], wf[4];
      #pragma unroll
      for (int mi=0;mi<4;mi++)
        hf[mi] = *(const s16x8*)&Hb[(wr*64+mi*16+lc)*64 + (((kt*4+lr) ^ ((wr*64+mi*16+lc)&7))*8)];
      #pragma unroll
      for (int nj=0;nj<4;nj++)
        wf[nj] = *(const s16x8*)&W2T[(size_t)(wc*64+nj*16+lc)*512 + ck*64 + kt*32 + lr*8];
      #pragma unroll
      for (int mi=0;mi<4;mi++)
        #pragma unroll
        for (int nj=0;nj<4;nj++)
          oacc[mi][nj] = __builtin_amdgcn_mfma_f32_16x16x32_bf16(hf[mi], wf[nj], oacc[mi][nj], 0,0,0);
    }
  }

  // ---- adapter1: a2 = A1 x Xn -> D[hid@lr*4+r][tok@lc], hid<32 ----
  f32x4 a2[4][2];
  #pragma unroll
  for (int mi=0;mi<4;mi++){ a2[mi][0]=(f32x4){0.f,0.f,0.f,0.f}; a2[mi][1]=(f32x4){0.f,0.f,0.f,0.f}; }
  #pragma unroll
  for (int kt=0; kt<4; kt++){
    s16x8 af[4];
    #pragma unroll
    for (int mi=0;mi<4;mi++)
      af[mi] = *(const s16x8*)&As[(wr*64+mi*16+lc)*128 + (((kt*4+lr) ^ (lc&7))*8)];
    s16x8 bA = *(const s16x8*)&A1T[(size_t)lc*128 + kt*32 + lr*8];
    s16x8 bB = *(const s16x8*)&A1T[(size_t)(16+lc)*128 + kt*32 + lr*8];
    #pragma unroll
    for (int mi=0;mi<4;mi++){
      a2[mi][0] = __builtin_amdgcn_mfma_f32_16x16x32_bf16(bA, af[mi], a2[mi][0], 0,0,0);
      a2[mi][1] = __builtin_amdgcn_mfma_f32_16x16x32_bf16(bB, af[mi], a2[mi][1], 0,0,0);
    }
  }
  __syncthreads();   // all Xn reads of As done; last chunk's Hb reads done
  // ---- Hq (x0.5 folded) -> As[tok*64 + swz(hid)] (16B-aligned slots) ----
  if (wc==0){
    #pragma unroll
    for (int nj=0;nj<2;nj++){
      const int hb = nj*16 + lr*4;
      float4 b4 = *(const float4*)&ab1[hb];
      #pragma unroll
      for (int mi=0;mi<4;mi++){
        const int tok = wr*64 + mi*16 + lc;
        uint2 pk;
        pk.x = cvtpk(0.5f*gelu_f(a2[mi][nj][0]+b4.x), 0.5f*gelu_f(a2[mi][nj][1]+b4.y));
        pk.y = cvtpk(0.5f*gelu_f(a2[mi][nj][2]+b4.z), 0.5f*gelu_f(a2[mi][nj][3]+b4.w));
        *(uint2*)&As[tok*64 + (((hb>>3) ^ (tok&7))*8) + (hb&7)] = pk;
      }
    }
  }
  __syncthreads();
  // ---- adapter2: oacc += Hq x A2 (K=32, one mfma per tile) ----
  {
    s16x8 hqf[4];
    #pragma unroll
    for (int mi=0;mi<4;mi++){
      const int tok = wr*64 + mi*16 + lc;
      hqf[mi] = *(const s16x8*)&As[tok*64 + ((lr ^ (tok&7))*8)];
    }
    #pragma unroll
    for (int nj=0;nj<4;nj++){
      s16x8 a2f = *(const s16x8*)&A2T[(size_t)(wc*64+nj*16+lc)*32 + lr*8];
      #pragma unroll
      for (int mi=0;mi<4;mi++)
        oacc[mi][nj] = __builtin_amdgcn_mfma_f32_16x16x32_bf16(hqf[mi], a2f, oacc[mi][nj], 0,0,0);
    }
  }
  // ---- epilogue: out += oacc + b2 + 0.5*ab2 (64B-coalesced scalar f32 RMW) ----
  #pragma unroll
  for (int nj=0;nj<4;nj++){
    const int col = wc*64 + nj*16 + lc;
    const float badd = b2[col] + 0.5f*ab2[col];
    #pragma unroll
    for (int mi=0;mi<4;mi++){
      #pragma unroll
      for (int r=0;r<4;r++){
        const size_t row = row0 + wr*64 + mi*16 + lr*4 + r;
        outp[row*128 + col] += oacc[mi][nj][r] + badd;
      }
    }
  }
}

// ---------------- temporal attention (T=8 per (b,l), 4 heads), bf16 out ----------------
__global__ __launch_bounds__(256) void t_attn_kernel(const u16* __restrict__ qkv,
    const float* __restrict__ tpb, u16* __restrict__ o)
{
  const int tid = threadIdx.x;
  const int li = tid>>5, h = (tid>>3)&3, t = tid&7;
  const int b = blockIdx.x/392, lt = blockIdx.x%392;
  const int l = lt*8+li;
  const size_t rowt = (size_t)(b*8+t)*LDIM + l;
  const u16* qp = qkv + rowt*384 + h*32;
  f32x8 q0 = ldbf8(qp)   *SCALE_F, q1 = ldbf8(qp+8) *SCALE_F,
        q2 = ldbf8(qp+16)*SCALE_F, q3 = ldbf8(qp+24)*SCALE_F;
  float s[8];
  #pragma unroll
  for (int t2=0;t2<8;t2++){
    const u16* kp = qkv + ((size_t)(b*8+t2)*LDIM + l)*384 + 128 + h*32;
    f32x8 d = q0*ldbf8(kp) + q1*ldbf8(kp+8) + q2*ldbf8(kp+16) + q3*ldbf8(kp+24);
    s[t2] = sum8(d) + tpb[(t-t2+7)*4 + h];
  }
  float m = s[0];
  #pragma unroll
  for (int t2=1;t2<8;t2++) m = fmaxf(m, s[t2]);
  float ssum = 0.f;
  #pragma unroll
  for (int t2=0;t2<8;t2++){ s[t2] = __expf(s[t2]-m); ssum += s[t2]; }
  const float inv = 1.0f/ssum;
  f32x8 o0={0,0,0,0,0,0,0,0}, o1={0,0,0,0,0,0,0,0},
        o2={0,0,0,0,0,0,0,0}, o3={0,0,0,0,0,0,0,0};
  #pragma unroll
  for (int t2=0;t2<8;t2++){
    const u16* vp = qkv + ((size_t)(b*8+t2)*LDIM + l)*384 + 256 + h*32;
    float aw = s[t2]*inv;
    o0 += aw*ldbf8(vp); o1 += aw*ldbf8(vp+8); o2 += aw*ldbf8(vp+16); o3 += aw*ldbf8(vp+24);
  }
  u16* op = o + rowt*128 + h*32;
  *(u16x8*)op      = pack8(o0); *(u16x8*)(op+8)  = pack8(o1);
  *(u16x8*)(op+16) = pack8(o2); *(u16x8*)(op+24) = pack8(o3);
}

// --------- MFMA shifted-window spatial attention ---------
__global__ __launch_bounds__(256,2) void s_attn_mfma(const u16* __restrict__ qkv,
    const float* __restrict__ rpb, u16* __restrict__ o)
{
  __shared__ u16 Qs[64][136];
  __shared__ u16 Ks[64][136];
  __shared__ u16 Vt[128][72];
  __shared__ float rpbL[676];
  __shared__ int rowL[49];
  __shared__ int codeL[49];
  const int tid = threadIdx.x;
  const int bidx = blockIdx.x;
  const int bt = bidx>>6, wh = (bidx>>3)&7, ww = bidx&7;
  if (tid < 49){
    int ph = tid/7, pwv = tid%7;
    int rh = wh*7+ph, rw = ww*7+pwv;
    int oh = rh+3; if (oh>=56) oh-=56;   // roll(-3)
    int ow = rw+3; if (ow>=56) ow-=56;
    rowL[tid] = bt*LDIM + oh*56 + ow;
    codeL[tid] = ((rh<49)?0:((rh<53)?1:2))*3 + ((rw<49)?0:((rw<53)?1:2));
  }
  for (int i2 = tid; i2 < 676; i2 += 256) rpbL[i2] = rpb[i2];
  for (int idx = tid; idx < 128*15; idx += 256){
    int d = idx/15, jj = 49 + (idx - d*15);
    Vt[d][jj] = 0;
  }
  __syncthreads();
  #pragma unroll
  for (int it = 0; it < 10; it++){
    int idx = it*256 + tid;
    if (idx < 2352){
      int j = idx/48, s = idx - j*48;
      const u16* src = qkv + (size_t)rowL[j]*384 + s*8;
      u16x8 v = *(const u16x8*)src;
      if (s < 16)      *(u16x8*)&Qs[j][s*8] = v;
      else if (s < 32) *(u16x8*)&Ks[j][(s-16)*8] = v;
      else { int c0 = (s-32)*8;
        #pragma unroll
        for (int e=0;e<8;e++) Vt[c0+e][j] = v[e];
      }
    }
  }
  __syncthreads();

  const int h = tid>>6, lane = tid&63, lr = lane>>4, lc = lane&15;
  s16x8 qf[4], kf[4];
  #pragma unroll
  for (int t=0;t<4;t++){
    qf[t] = *(const s16x8*)&Qs[t*16+lc][h*32+lr*8];
    kf[t] = *(const s16x8*)&Ks[t*16+lc][h*32+lr*8];
  }
  f32x4 sa[4][4];
  #pragma unroll
  for (int tj=0;tj<4;tj++){
    #pragma unroll
    for (int ti=0;ti<4;ti++)
      sa[tj][ti] = __builtin_amdgcn_mfma_f32_16x16x32_bf16(kf[tj], qf[ti], (f32x4){0.f,0.f,0.f,0.f}, 0,0,0);
  }
  int ihv[4], iwv[4], civ[4];
  #pragma unroll
  for (int ti=0;ti<4;ti++){
    int i = ti*16+lc; int im = (i<49)? i:48;
    int ih2 = (im*147)>>10; ihv[ti]=ih2; iwv[ti]=im-ih2*7; civ[ti]=codeL[im];
  }
  float rs[4] = {0.f,0.f,0.f,0.f};
  #pragma unroll
  for (int tj=0;tj<4;tj++){
    #pragma unroll
    for (int r=0;r<4;r++){
      int j = tj*16 + lr*4 + r;
      bool jv = (j<49);
      int jm = jv? j:48;
      int jh2 = (jm*147)>>10; int jw2 = jm - jh2*7; int cj = codeL[jm];
      #pragma unroll
      for (int ti=0;ti<4;ti++){
        float sv = sa[tj][ti][r]*SCALE_F
                 + rpbL[((ihv[ti]-jh2+6)*13 + (iwv[ti]-jw2+6))*4 + h];
        if (civ[ti] != cj) sv -= 100.f;
        float pv = jv ? __expf(sv) : 0.f;
        sa[tj][ti][r] = pv;
        rs[ti] += pv;
      }
    }
  }
  #pragma unroll
  for (int ti=0;ti<4;ti++){
    float t2 = rs[ti];
    t2 += __shfl_xor(t2, 16);
    t2 += __shfl_xor(t2, 32);
    rs[ti] = 1.0f/t2;
  }
  unsigned lo[4][4], hi[4][4];
  #pragma unroll
  for (int tj=0;tj<4;tj++){
    #pragma unroll
    for (int ti=0;ti<4;ti++){
      float inv = rs[ti];
      lo[tj][ti] = cvtpk(sa[tj][ti][0]*inv, sa[tj][ti][1]*inv);
      hi[tj][ti] = cvtpk(sa[tj][ti][2]*inv, sa[tj][ti][3]*inv);
    }
  }
  f32x4 oa[4][2];
  #pragma unroll
  for (int mi=0;mi<4;mi++){ oa[mi][0]=(f32x4){0.f,0.f,0.f,0.f}; oa[mi][1]=(f32x4){0.f,0.f,0.f,0.f}; }
  const int srcA = lc + ((lane>>4)&1)*32;
  const int srcB = srcA + 16;
  const bool hiHalf = (lr>=2);
  #pragma unroll
  for (int kt=0;kt<2;kt++){
    s16x8 vf[2];
    #pragma unroll
    for (int nd=0;nd<2;nd++)
      vf[nd] = *(const s16x8*)&Vt[h*32 + nd*16 + lc][kt*32 + lr*8];
    #pragma unroll
    for (int mi=0;mi<4;mi++){
      unsigned wA0 = __shfl(lo[2*kt][mi],   srcA), wB0 = __shfl(lo[2*kt+1][mi], srcA);
      unsigned wA1 = __shfl(hi[2*kt][mi],   srcA), wB1 = __shfl(hi[2*kt+1][mi], srcA);
      unsigned wA2 = __shfl(lo[2*kt][mi],   srcB), wB2 = __shfl(lo[2*kt+1][mi], srcB);
      unsigned wA3 = __shfl(hi[2*kt][mi],   srcB), wB3 = __shfl(hi[2*kt+1][mi], srcB);
      union { unsigned u[4]; s16x8 v8; } cv;
      cv.u[0] = hiHalf? wB0 : wA0;
      cv.u[1] = hiHalf? wB1 : wA1;
      cv.u[2] = hiHalf? wB2 : wA2;
      cv.u[3] = hiHalf? wB3 : wA3;
      #pragma unroll
      for (int nd=0;nd<2;nd++)
        oa[mi][nd] = __builtin_amdgcn_mfma_f32_16x16x32_bf16(cv.v8, vf[nd], oa[mi][nd], 0,0,0);
    }
  }
  #pragma unroll
  for (int mi=0;mi<4;mi++){
    #pragma unroll
    for (int r=0;r<4;r++){
      int i = mi*16 + lr*4 + r;
      if (i < 49){
        size_t orow = (size_t)rowL[i]*128 + h*32;
        o[orow + lc]      = f2bf(oa[mi][0][r]);
        o[orow + 16 + lc] = f2bf(oa[mi][1][r]);
      }
    }
  }
}

extern "C" void kernel_launch(void* const* d_in, const int* in_sizes, int n_in,
                              void* d_out, int out_size, void* d_ws, size_t ws_size,
                              hipStream_t stream)
{
  (void)in_sizes; (void)n_in; (void)out_size; (void)ws_size;
  const float* x      = (const float*)d_in[0];
  const float* qkv_w  = (const float*)d_in[1];
  const float* qkv_b  = (const float*)d_in[2];
  const float* proj_w = (const float*)d_in[3];
  const float* proj_b = (const float*)d_in[4];
  const float* rpb    = (const float*)d_in[5];
  const float* tpb    = (const float*)d_in[6];
  const float* n1g    = (const float*)d_in[7];
  const float* n1b    = (const float*)d_in[8];
  const float* n2g    = (const float*)d_in[9];
  const float* n2b    = (const float*)d_in[10];
  const float* mw1    = (const float*)d_in[11];
  const float* mb1    = (const float*)d_in[12];
  const float* mw2    = (const float*)d_in[13];
  const float* mb2    = (const float*)d_in[14];
  const float* sw1    = (const float*)d_in[15];
  const float* sb1    = (const float*)d_in[16];
  const float* sw2    = (const float*)d_in[17];
  const float* sb2    = (const float*)d_in[18];
  const float* tw1    = (const float*)d_in[19];
  const float* tb1    = (const float*)d_in[20];
  const float* tw2    = (const float*)d_in[21];
  const float* tb2    = (const float*)d_in[22];
  const float* aw1    = (const float*)d_in[23];
  const float* ab1    = (const float*)d_in[24];
  const float* aw2    = (const float*)d_in[25];
  const float* ab2    = (const float*)d_in[26];

  char* ws = (char*)d_ws;
  u16*   Xn  = (u16*)(ws);
  u16*   QKV = (u16*)(ws + 25690112ULL);
  u16*   O   = (u16*)(ws + 102760448ULL);
  float* Cb  = (float*)(ws + 134873088ULL);
  u16*   WT  = (u16*)(ws + 186253312ULL);
  float* out = (float*)d_out;

  const u16 *WTqkv=WT, *WTproj=WT+49152, *WTm1=WT+65536, *WTm2=WT+131072,
            *WTt1=WT+196608, *WTt2=WT+200704, *WTs1=WT+204800, *WTs2=WT+208896,
            *WTa1=WT+212992, *WTa2=WT+217088;

  WSrc srcs; srcs.p[0]=qkv_w; srcs.p[1]=proj_w; srcs.p[2]=mw1; srcs.p[3]=mw2;
  srcs.p[4]=tw1; srcs.p[5]=tw2; srcs.p[6]=sw1; srcs.p[7]=sw2; srcs.p[8]=aw1; srcs.p[9]=aw2;
  prep_w<<<864,256,0,stream>>>(srcs, WT);

  // ---- temporal attention + T_Adapter (+fused LN of its output) ----
  ln_kernel<<<25088,256,0,stream>>>(x, n1g, n1b, Xn);
  gemm_tile<1,3,0><<<784,256,0,stream>>>(Xn, WTqkv, qkv_b, QKV, 384, nullptr,nullptr);
  t_attn_kernel<<<1568,256,0,stream>>>(QKV, tpb, O);
  proj_ada_tile<0><<<784,256,0,stream>>>(O, WTproj, proj_b, WTt1, tb1, WTt2, tb2,
                                          x, Cb, n1g, n1b, Xn);
  // ---- shifted-window spatial attention + S_Adapter (+fused LN2) ----
  gemm_tile<1,3,0><<<784,256,0,stream>>>(Xn, WTqkv, qkv_b, QKV, 384, nullptr,nullptr);
  s_attn_mfma<<<2048,256,0,stream>>>(QKV, rpb, O);
  proj_ada_tile<1><<<784,256,0,stream>>>(O, WTproj, proj_b, WTs1, sb1, WTs2, sb2,
                                          Cb, out, n2g, n2b, Xn);
  // ---- fully fused MLP + MLP_Adapter (v4) ----
  mlp_fused<<<784,256,0,stream>>>(Xn, WTm1, mb1, WTm2, mb2, WTa1, ab1, WTa2, ab2, out);
}